// Round 1
// baseline (326.055 us; speedup 1.0000x reference)
//
#include <hip/hip_runtime.h>
#include <math.h>

#define NB   8
#define SEQ  1024
#define CH   768
#define NH   12
#define HD   64
#define BHT  (NB * NH)    // 96
#define QKVN 2304         // 3*CH

typedef unsigned short u16;
typedef unsigned int   u32;
typedef __attribute__((ext_vector_type(8))) short bf16x8;  // 8 bf16 (4 VGPRs)
typedef __attribute__((ext_vector_type(4))) float f32x4;   // MFMA acc

__device__ __forceinline__ float bf2f(u32 s) {
    union { u32 u; float f; } v; v.u = s << 16; return v.f;
}
__device__ __forceinline__ u16 f2bf(float f) {
    union { float f; u32 u; } v; v.f = f;
    u32 u = v.u;
    return (u16)((u + 0x7fffu + ((u >> 16) & 1u)) >> 16);  // RNE, finite inputs
}
// packed f32x2 -> bf16x2 (RNE), single VALU instr
__device__ __forceinline__ u32 cvtpk(float lo, float hi) {
    u32 r;
    asm("v_cvt_pk_bf16_f32 %0, %1, %2" : "=v"(r) : "v"(lo), "v"(hi));
    return r;
}
__device__ __forceinline__ float ld1(const u16* p) { return bf2f((u32)*p); }
__device__ __forceinline__ void st4v(u16* p, float a, float b, float c, float d) {
    ushort4 o; o.x = f2bf(a); o.y = f2bf(b); o.z = f2bf(c); o.w = f2bf(d);
    *(ushort4*)p = o;
}
__device__ __forceinline__ void st4v(float* p, float a, float b, float c, float d) {
    float4 o; o.x = a; o.y = b; o.z = c; o.w = d;
    *(float4*)p = o;
}
// async global->LDS, 16B per lane, dest = wave-uniform base + lane*16
__device__ __forceinline__ void gload16(const u16* g, u16* l) {
    __builtin_amdgcn_global_load_lds(
        (const __attribute__((address_space(1))) void*)g,
        (__attribute__((address_space(3))) void*)l, 16, 0, 0);
}

// ---------------------------------------------------------------------------
// dtype detect (proven): flag 1 = bf16 inputs, 0 = fp32 inputs
// ---------------------------------------------------------------------------
__global__ void detect_kernel(const u32* __restrict__ x, int* __restrict__ flag) {
    __shared__ int cnt;
    if (threadIdx.x == 0) cnt = 0;
    __syncthreads();
    int c = 0;
    for (int i = threadIdx.x; i < 2048; i += 256) {
        const u32 e0 = (x[i] >> 7) & 0xFFu;
        c += (e0 >= 110u && e0 <= 132u) ? 1 : 0;
    }
    atomicAdd(&cnt, c);
    __syncthreads();
    if (threadIdx.x == 0) *flag = (cnt > 1024) ? 1 : 0;
}

// ---------------------------------------------------------------------------
// Prep: inputs -> one contiguous bf16 arena in ws. Unified (one launch):
// block-uniform branch on dtype flag.
// ---------------------------------------------------------------------------
#define PREP_V4 5309184
__device__ __forceinline__ void prep_seg(size_t v, const size_t e0[6],
                                         int* segp, size_t* offp) {
    int seg = 5;
    if      (v < 1572864) seg = 0;
    else if (v < 2015232) seg = 1;
    else if (v < 2015808) seg = 2;
    else if (v < 5161536) seg = 3;
    else if (v < 5308992) seg = 4;
    *segp = seg; *offp = v * 4 - e0[seg];
}

__global__ __launch_bounds__(256) void prep_all(
    const int* __restrict__ flag,
    const void* __restrict__ s0, const void* __restrict__ s1, const void* __restrict__ s2,
    const void* __restrict__ s3, const void* __restrict__ s4, const void* __restrict__ s5,
    u16* __restrict__ dst)
{
    const size_t e0[6] = {0, 6291456, 8060928, 8063232, 20646144, 21235968};
    if (*flag != 0) {
        const u16* const srcs[6] = {(const u16*)s0, (const u16*)s1, (const u16*)s2,
                                    (const u16*)s3, (const u16*)s4, (const u16*)s5};
        for (size_t v = blockIdx.x * 256 + threadIdx.x; v < PREP_V4; v += (size_t)gridDim.x * 256) {
            int seg; size_t off;
            prep_seg(v, e0, &seg, &off);
            *(ushort4*)(dst + v * 4) = *(const ushort4*)(srcs[seg] + off);
        }
    } else {
        const float* const srcs[6] = {(const float*)s0, (const float*)s1, (const float*)s2,
                                      (const float*)s3, (const float*)s4, (const float*)s5};
        for (size_t v = blockIdx.x * 256 + threadIdx.x; v < PREP_V4; v += (size_t)gridDim.x * 256) {
            int seg; size_t off;
            prep_seg(v, e0, &seg, &off);
            const float4 f = *(const float4*)(srcs[seg] + off);
            ushort4 o; o.x = f2bf(f.x); o.y = f2bf(f.y); o.z = f2bf(f.z); o.w = f2bf(f.w);
            *(ushort4*)(dst + v * 4) = o;
        }
    }
}

// ---------------------------------------------------------------------------
// 128x128 MFMA GEMM core, m97-style global_load_lds staging.
// LDS [128 rows][32 u16], unpadded; 16B k-chunk at column c of row r holds
// global chunk (c + r) & 3  (source-side rotation -> 2-way-free frag reads).
// SWAP=true computes C^T (n on (quad,reg), m on l15) for vectorized stores.
// ---------------------------------------------------------------------------
template<bool SWAP>
__device__ __forceinline__ void gemm128_core(
    const u16* __restrict__ Ag, const u16* __restrict__ Bg,   // tile row-0 bases
    f32x4 acc[4][4], u16* As, u16* Bs, int wm, int wn, int l15, int quad)
{
    const int t = threadIdx.x;
    const int w = t >> 6, lane = t & 63;
    const int lr = lane >> 2, lc = lane & 3;
    const int r0 = w * 16 + lr;            // rows 0..63   (issue 0)
    const int r1 = 64 + w * 16 + lr;       // rows 64..127 (issue 1)
    const int g0 = (lc + r0) & 3, g1 = (lc + r1) & 3;
    const u16* a0 = Ag + (size_t)r0 * CH + g0 * 8;
    const u16* a1 = Ag + (size_t)r1 * CH + g1 * 8;
    const u16* b0 = Bg + (size_t)r0 * CH + g0 * 8;
    const u16* b1 = Bg + (size_t)r1 * CH + g1 * 8;
    u16* lA0 = As + w * 512;               // 16 rows * 32 u16 = 1 KB per wave-issue
    u16* lA1 = As + 2048 + w * 512;
    u16* lB0 = Bs + w * 512;
    u16* lB1 = Bs + 2048 + w * 512;

#pragma unroll
    for (int mi = 0; mi < 4; mi++)
#pragma unroll
        for (int ni = 0; ni < 4; ni++) { f32x4 z = {0.f,0.f,0.f,0.f}; acc[mi][ni] = z; }

    for (int k0 = 0; k0 < CH; k0 += 32) {
        __syncthreads();                   // prev iter's frag reads done
        gload16(a0 + k0, lA0);
        gload16(a1 + k0, lA1);
        gload16(b0 + k0, lB0);
        gload16(b1 + k0, lB1);
        __syncthreads();                   // drains vmcnt (loads landed)
        bf16x8 af[4], bfr[4];
#pragma unroll
        for (int mi = 0; mi < 4; mi++) {
            const int ra = wm * 64 + mi * 16 + l15;
            af[mi] = *(const bf16x8*)&As[ra * 32 + ((quad - ra) & 3) * 8];
        }
#pragma unroll
        for (int ni = 0; ni < 4; ni++) {
            const int rb = wn * 64 + ni * 16 + l15;
            bfr[ni] = *(const bf16x8*)&Bs[rb * 32 + ((quad - rb) & 3) * 8];
        }
#pragma unroll
        for (int mi = 0; mi < 4; mi++)
#pragma unroll
            for (int ni = 0; ni < 4; ni++)
                acc[mi][ni] = SWAP
                    ? __builtin_amdgcn_mfma_f32_16x16x32_bf16(bfr[ni], af[mi], acc[mi][ni], 0, 0, 0)
                    : __builtin_amdgcn_mfma_f32_16x16x32_bf16(af[mi], bfr[ni], acc[mi][ni], 0, 0, 0);
    }
}

// ---------------------------------------------------------------------------
// Kernel 1: QKV projection. grid (18,64), block 256.
// Q/K: SWAP path -> vectorized natural stores [BH][SEQ][D] (Q pre-scaled).
// V: standard path -> vectorized transposed stores [BH][D][SEQ].
// ---------------------------------------------------------------------------
__global__ __launch_bounds__(256) void qkv_gemm(
    const u16* __restrict__ x, const u16* __restrict__ w, const u16* __restrict__ bias,
    u16* __restrict__ Qn, u16* __restrict__ Kn, u16* __restrict__ Vt)
{
    __shared__ u16 As[128 * 32];
    __shared__ u16 Bs[128 * 32];
    const int t = threadIdx.x, lane = t & 63, wv = t >> 6;
    const int l15 = lane & 15, quad = lane >> 4;
    const int wm = wv >> 1, wn = wv & 1;
    const int m0 = blockIdx.y * 128, n0 = blockIdx.x * 128;
    const int which = n0 / CH;                 // 0=q 1=k 2=v (block-uniform)
    const int h     = ((n0 % CH) >> 6) + wn;   // wave-uniform
    const int b     = m0 >> 10;
    const size_t bh = (size_t)b * NH + h;
    const int sq0   = m0 & 1023;
    f32x4 acc[4][4];

    if (which == 2) {
        gemm128_core<false>(x + (size_t)m0 * CH, w + (size_t)n0 * CH,
                            acc, As, Bs, wm, wn, l15, quad);
        float bv[4];
#pragma unroll
        for (int ni = 0; ni < 4; ni++) bv[ni] = ld1(bias + n0 + wn * 64 + ni * 16 + l15);
#pragma unroll
        for (int mi = 0; mi < 4; mi++) {
            const int seq = sq0 + wm * 64 + mi * 16 + quad * 4;
#pragma unroll
            for (int ni = 0; ni < 4; ni++) {
                const int d = ni * 16 + l15;
                st4v(&Vt[(bh * HD + d) * SEQ + seq],
                     acc[mi][ni][0] + bv[ni], acc[mi][ni][1] + bv[ni],
                     acc[mi][ni][2] + bv[ni], acc[mi][ni][3] + bv[ni]);
            }
        }
    } else {
        gemm128_core<true>(x + (size_t)m0 * CH, w + (size_t)n0 * CH,
                           acc, As, Bs, wm, wn, l15, quad);
        u16* T2 = which ? Kn : Qn;
        const float qsc = which ? 1.0f : 0.125f;   // D^-0.5 folded into q
        float bvr[4][4];
#pragma unroll
        for (int ni = 0; ni < 4; ni++)
#pragma unroll
            for (int r = 0; r < 4; r++)
                bvr[ni][r] = ld1(bias + n0 + wn * 64 + ni * 16 + quad * 4 + r);
#pragma unroll
        for (int mi = 0; mi < 4; mi++) {
            const int seq = sq0 + wm * 64 + mi * 16 + l15;
#pragma unroll
            for (int ni = 0; ni < 4; ni++) {
                const int dbase = ni * 16 + quad * 4;
                st4v(&T2[(bh * SEQ + seq) * HD + dbase],
                     (acc[mi][ni][0] + bvr[ni][0]) * qsc,
                     (acc[mi][ni][1] + bvr[ni][1]) * qsc,
                     (acc[mi][ni][2] + bvr[ni][2]) * qsc,
                     (acc[mi][ni][3] + bvr[ni][3]) * qsc);
            }
        }
    }
}

// ---------------------------------------------------------------------------
// Kernel 2: MFMA attention, barrier-free. grid (8,96), block 256.
// K/V fragments read DIRECTLY from global (per-(b,h) K+V = 256 KB, L2-fits;
// LDS staging + both per-tile barriers removed — cf. learn_hip m169).
// QK^T operand-swapped: S^T[j on (quad,r)][i on l15]; P packed with
// v_cvt_pk_bf16_f32 into [i][j] LDS (8x ds_write_b64/tile, conflict-free,
// double-buffered), row-sum rl is a plain per-lane accumulate.
// PV/AV swapped operands -> D[d on (quad,r)][i on l15], vectorized AO stores.
// ---------------------------------------------------------------------------
__global__ __launch_bounds__(256, 3) void attn_kernel(
    const u16* __restrict__ Qn, const u16* __restrict__ Kn, const u16* __restrict__ Vt,
    const u16* __restrict__ Ab, u16* __restrict__ AO)
{
    __shared__ u16 Ps[8 * 32 * 72];    // per-wave P [i][j] stride 72, x2 dbuf

    const int qb = blockIdx.x;
    const int y  = blockIdx.y;
    const int hh = y >> 3, b = y & 7;           // A-locality decode (same XCD)
    const size_t bh = (size_t)b * NH + hh;
    const int t  = threadIdx.x;
    const int w  = t >> 6, lane = t & 63;
    const int l15 = lane & 15, quad = lane >> 4;
    const int i0g = qb * 128 + w * 32;          // wave's first query (in-batch)

    const u16* Kb  = Kn + bh * SEQ * HD;
    const u16* Vb  = Vt + bh * HD * SEQ;
    const u16* Abr = Ab + (size_t)hh * SEQ * SEQ;

    // Q fragments, loaded once (Qn pre-scaled by D^-0.5).
    // Same register data serves as B-operand of mfma(K, Q) (A-frag of Q == B-frag of Q^T).
    bf16x8 qa[2][2];
#pragma unroll
    for (int isub = 0; isub < 2; isub++)
#pragma unroll
        for (int db = 0; db < 2; db++)
            qa[isub][db] = *(const bf16x8*)(Qn +
                (bh * SEQ + i0g + isub * 16 + l15) * HD + db * 32 + quad * 8);

    f32x4 Op[2][4], Oa[2][4];
#pragma unroll
    for (int i = 0; i < 2; i++)
#pragma unroll
        for (int d = 0; d < 4; d++) { f32x4 z = {0.f,0.f,0.f,0.f}; Op[i][d] = z; Oa[i][d] = z; }
    float rl[2] = {0.f, 0.f};

    for (int kt = 0; kt < 16; kt++) {
        const int j0 = kt * 64;
        u16* Psw = Ps + (w * 2 + (kt & 1)) * (32 * 72);   // dbuf kills WAR stall

        // A-bias fragments for this tile (B-operand of mfma(v, a)); latency
        // overlaps the whole QK phase.
        bf16x8 afr[2][2];
#pragma unroll
        for (int jb = 0; jb < 2; jb++)
#pragma unroll
            for (int isub = 0; isub < 2; isub++)
                afr[jb][isub] = *(const bf16x8*)(Abr +
                    (size_t)(i0g + isub * 16 + l15) * SEQ + j0 + jb * 32 + quad * 8);

        // ---- QK^T swapped: S^T[j = j16*16+quad*4+r][i = isub*16+l15]
#pragma unroll
        for (int j16 = 0; j16 < 4; j16++) {
            const u16* kr = Kb + (size_t)(j0 + j16 * 16 + l15) * HD + quad * 8;
            const bf16x8 kf0 = *(const bf16x8*)kr;
            const bf16x8 kf1 = *(const bf16x8*)(kr + 32);
#pragma unroll
            for (int isub = 0; isub < 2; isub++) {
                f32x4 s = {0.f, 0.f, 0.f, 0.f};
                __builtin_amdgcn_s_setprio(1);
                s = __builtin_amdgcn_mfma_f32_16x16x32_bf16(kf0, qa[isub][0], s, 0, 0, 0);
                s = __builtin_amdgcn_mfma_f32_16x16x32_bf16(kf1, qa[isub][1], s, 0, 0, 0);
                __builtin_amdgcn_s_setprio(0);
                const float p0 = __expf(fminf(s[0], 60.f));  // no inf, ever
                const float p1 = __expf(fminf(s[1], 60.f));
                const float p2 = __expf(fminf(s[2], 60.f));
                const float p3 = __expf(fminf(s[3], 60.f));
                rl[isub] += (p0 + p1) + (p2 + p3);
                uint2 u; u.x = cvtpk(p0, p1); u.y = cvtpk(p2, p3);
                *(uint2*)&Psw[(isub * 16 + l15) * 72 + j16 * 16 + quad * 4] = u;
            }
        }

        // ---- PV + AV, swapped operands: D[d on (quad,r)][i on l15]
#pragma unroll
        for (int jb = 0; jb < 2; jb++) {
            const bf16x8 pf0 = *(const bf16x8*)&Psw[(l15) * 72 + jb * 32 + quad * 8];
            const bf16x8 pf1 = *(const bf16x8*)&Psw[(16 + l15) * 72 + jb * 32 + quad * 8];
            __builtin_amdgcn_s_setprio(1);
#pragma unroll
            for (int d16 = 0; d16 < 4; d16++) {
                const bf16x8 vf = *(const bf16x8*)(Vb +
                    (size_t)(d16 * 16 + l15) * SEQ + j0 + jb * 32 + quad * 8);
                Op[0][d16] = __builtin_amdgcn_mfma_f32_16x16x32_bf16(vf, pf0, Op[0][d16], 0, 0, 0);
                Oa[0][d16] = __builtin_amdgcn_mfma_f32_16x16x32_bf16(vf, afr[jb][0], Oa[0][d16], 0, 0, 0);
                Op[1][d16] = __builtin_amdgcn_mfma_f32_16x16x32_bf16(vf, pf1, Op[1][d16], 0, 0, 0);
                Oa[1][d16] = __builtin_amdgcn_mfma_f32_16x16x32_bf16(vf, afr[jb][1], Oa[1][d16], 0, 0, 0);
            }
            __builtin_amdgcn_s_setprio(0);
        }
    }

    // ---- finalize: rl held per-lane for col i=l15; sum the 4 quads
    float inv[2];
#pragma unroll
    for (int isub = 0; isub < 2; isub++) {
        float v = rl[isub];
        v += __shfl_xor(v, 16);
        v += __shfl_xor(v, 32);
        inv[isub] = 1.f / v;
    }
#pragma unroll
    for (int isub = 0; isub < 2; isub++) {
        const int n = i0g + isub * 16 + l15;
#pragma unroll
        for (int d16 = 0; d16 < 4; d16++)
            st4v(&AO[((size_t)b * SEQ + n) * CH + hh * HD + d16 * 16 + quad * 4],
                 Op[isub][d16][0] * inv[isub] + Oa[isub][d16][0],
                 Op[isub][d16][1] * inv[isub] + Oa[isub][d16][1],
                 Op[isub][d16][2] * inv[isub] + Oa[isub][d16][2],
                 Op[isub][d16][3] * inv[isub] + Oa[isub][d16][3]);
    }
}

// ---------------------------------------------------------------------------
// Kernel 3: out = AO @ proj_w^T + proj_b. grid (6,64), block 256. SWAP path
// -> vectorized float4/ushort4 stores. Unified: runtime branch on dtype flag
// in the epilogue (one launch instead of two).
// ---------------------------------------------------------------------------
__global__ __launch_bounds__(256) void proj_all(
    const int* __restrict__ flag,
    const u16* __restrict__ AO, const u16* __restrict__ w, const u16* __restrict__ bias,
    void* __restrict__ outv)
{
    __shared__ u16 As[128 * 32];
    __shared__ u16 Bs[128 * 32];
    const int isbf = *flag;
    const int t = threadIdx.x, lane = t & 63, wv = t >> 6;
    const int l15 = lane & 15, quad = lane >> 4;
    const int wm = wv >> 1, wn = wv & 1;
    const int m0 = blockIdx.y * 128, n0 = blockIdx.x * 128;

    f32x4 acc[4][4];
    gemm128_core<true>(AO + (size_t)m0 * CH, w + (size_t)n0 * CH,
                       acc, As, Bs, wm, wn, l15, quad);

    float bvr[4][4];
#pragma unroll
    for (int ni = 0; ni < 4; ni++)
#pragma unroll
        for (int r = 0; r < 4; r++)
            bvr[ni][r] = ld1(bias + n0 + wn * 64 + ni * 16 + quad * 4 + r);
#pragma unroll
    for (int mi = 0; mi < 4; mi++) {
        const int m = m0 + wm * 64 + mi * 16 + l15;
#pragma unroll
        for (int ni = 0; ni < 4; ni++) {
            const int n = n0 + wn * 64 + ni * 16 + quad * 4;
            if (isbf)
                st4v((u16*)outv + (size_t)m * CH + n,
                     acc[mi][ni][0] + bvr[ni][0], acc[mi][ni][1] + bvr[ni][1],
                     acc[mi][ni][2] + bvr[ni][2], acc[mi][ni][3] + bvr[ni][3]);
            else
                st4v((float*)outv + (size_t)m * CH + n,
                     acc[mi][ni][0] + bvr[ni][0], acc[mi][ni][1] + bvr[ni][1],
                     acc[mi][ni][2] + bvr[ni][2], acc[mi][ni][3] + bvr[ni][3]);
        }
    }
}

// ---------------------------------------------------------------------------
extern "C" void kernel_launch(void* const* d_in, const int* in_sizes, int n_in,
                              void* d_out, int out_size, void* d_ws, size_t ws_size,
                              hipStream_t stream) {
    (void)in_sizes; (void)n_in; (void)out_size; (void)ws_size;
    u16* ws = (u16*)d_ws;
    u16* xb   = ws;                 // 6,291,456
    u16* wqb  = ws + 6291456;       // 1,769,472
    u16* bqb  = ws + 8060928;       // 2,304
    u16* Ab   = ws + 8063232;       // 12,582,912
    u16* pwb  = ws + 20646144;      // 589,824
    u16* pbb  = ws + 21235968;      // 768
    u16* arena_end = ws + 21236736;
    const size_t S1 = (size_t)NB * NH * SEQ * HD;   // 6,291,456
    u16* Qn = arena_end;            // [BH][SEQ][D] bf16, pre-scaled
    u16* Kn = Qn + S1;              // [BH][SEQ][D]
    u16* Vt = Kn + S1;              // [BH][D][SEQ]
    u16* AO = Vt + S1;              // [B][SEQ][C]
    int* flag = (int*)(AO + S1);

    detect_kernel<<<dim3(1), dim3(256), 0, stream>>>((const u32*)d_in[0], flag);

    const dim3 blk(256);
    prep_all<<<dim3(4096), blk, 0, stream>>>(flag,
        d_in[0], d_in[1], d_in[2], d_in[3], d_in[4], d_in[5], ws);

    qkv_gemm<<<dim3(QKVN / 128, (NB * SEQ) / 128), blk, 0, stream>>>(
        xb, wqb, bqb, Qn, Kn, Vt);
    attn_kernel<<<dim3(SEQ / 128, BHT), blk, 0, stream>>>(Qn, Kn, Vt, Ab, AO);

    proj_all<<<dim3(CH / 128, (NB * SEQ) / 128), blk, 0, stream>>>(
        flag, AO, pwb, pbb, d_out);
}

// Round 2
// 287.431 us; speedup vs baseline: 1.1344x; 1.1344x over previous
//
#include <hip/hip_runtime.h>
#include <math.h>

#define NB   8
#define SEQ  1024
#define CH   768
#define NH   12
#define HD   64
#define BHT  (NB * NH)    // 96
#define QKVN 2304         // 3*CH

typedef unsigned short u16;
typedef unsigned int   u32;
typedef __attribute__((ext_vector_type(8))) short bf16x8;  // 8 bf16 (4 VGPRs)
typedef __attribute__((ext_vector_type(4))) float f32x4;   // MFMA acc

__device__ __forceinline__ float bf2f(u32 s) {
    union { u32 u; float f; } v; v.u = s << 16; return v.f;
}
__device__ __forceinline__ u16 f2bf(float f) {
    union { float f; u32 u; } v; v.f = f;
    u32 u = v.u;
    return (u16)((u + 0x7fffu + ((u >> 16) & 1u)) >> 16);  // RNE, finite inputs
}
// packed f32x2 -> bf16x2 (RNE), single VALU instr
__device__ __forceinline__ u32 cvtpk(float lo, float hi) {
    u32 r;
    asm("v_cvt_pk_bf16_f32 %0, %1, %2" : "=v"(r) : "v"(lo), "v"(hi));
    return r;
}
__device__ __forceinline__ float ld1(const u16* p) { return bf2f((u32)*p); }
__device__ __forceinline__ void st4v(u16* p, float a, float b, float c, float d) {
    ushort4 o; o.x = f2bf(a); o.y = f2bf(b); o.z = f2bf(c); o.w = f2bf(d);
    *(ushort4*)p = o;
}
__device__ __forceinline__ void st4v(float* p, float a, float b, float c, float d) {
    float4 o; o.x = a; o.y = b; o.z = c; o.w = d;
    *(float4*)p = o;
}
// async global->LDS, 16B per lane, dest = wave-uniform base + lane*16
__device__ __forceinline__ void gload16(const u16* g, u16* l) {
    __builtin_amdgcn_global_load_lds(
        (const __attribute__((address_space(1))) void*)g,
        (__attribute__((address_space(3))) void*)l, 16, 0, 0);
}

// ---------------------------------------------------------------------------
// dtype detect (proven): flag 1 = bf16 inputs, 0 = fp32 inputs
// ---------------------------------------------------------------------------
__global__ void detect_kernel(const u32* __restrict__ x, int* __restrict__ flag) {
    __shared__ int cnt;
    if (threadIdx.x == 0) cnt = 0;
    __syncthreads();
    int c = 0;
    for (int i = threadIdx.x; i < 2048; i += 256) {
        const u32 e0 = (x[i] >> 7) & 0xFFu;
        c += (e0 >= 110u && e0 <= 132u) ? 1 : 0;
    }
    atomicAdd(&cnt, c);
    __syncthreads();
    if (threadIdx.x == 0) *flag = (cnt > 1024) ? 1 : 0;
}

// ---------------------------------------------------------------------------
// Prep: inputs -> one contiguous bf16 arena in ws. Unified (one launch):
// block-uniform branch on dtype flag.
// ---------------------------------------------------------------------------
#define PREP_V4 5309184
__device__ __forceinline__ void prep_seg(size_t v, const size_t e0[6],
                                         int* segp, size_t* offp) {
    int seg = 5;
    if      (v < 1572864) seg = 0;
    else if (v < 2015232) seg = 1;
    else if (v < 2015808) seg = 2;
    else if (v < 5161536) seg = 3;
    else if (v < 5308992) seg = 4;
    *segp = seg; *offp = v * 4 - e0[seg];
}

__global__ __launch_bounds__(256) void prep_all(
    const int* __restrict__ flag,
    const void* __restrict__ s0, const void* __restrict__ s1, const void* __restrict__ s2,
    const void* __restrict__ s3, const void* __restrict__ s4, const void* __restrict__ s5,
    u16* __restrict__ dst)
{
    const size_t e0[6] = {0, 6291456, 8060928, 8063232, 20646144, 21235968};
    if (*flag != 0) {
        const u16* const srcs[6] = {(const u16*)s0, (const u16*)s1, (const u16*)s2,
                                    (const u16*)s3, (const u16*)s4, (const u16*)s5};
        for (size_t v = blockIdx.x * 256 + threadIdx.x; v < PREP_V4; v += (size_t)gridDim.x * 256) {
            int seg; size_t off;
            prep_seg(v, e0, &seg, &off);
            *(ushort4*)(dst + v * 4) = *(const ushort4*)(srcs[seg] + off);
        }
    } else {
        const float* const srcs[6] = {(const float*)s0, (const float*)s1, (const float*)s2,
                                      (const float*)s3, (const float*)s4, (const float*)s5};
        for (size_t v = blockIdx.x * 256 + threadIdx.x; v < PREP_V4; v += (size_t)gridDim.x * 256) {
            int seg; size_t off;
            prep_seg(v, e0, &seg, &off);
            const float4 f = *(const float4*)(srcs[seg] + off);
            ushort4 o; o.x = f2bf(f.x); o.y = f2bf(f.y); o.z = f2bf(f.z); o.w = f2bf(f.w);
            *(ushort4*)(dst + v * 4) = o;
        }
    }
}

// ---------------------------------------------------------------------------
// 128x128 MFMA GEMM core, m97-style global_load_lds staging.
// LDS [128 rows][32 u16], unpadded; 16B k-chunk at column c of row r holds
// global chunk (c + r) & 3  (source-side rotation -> 2-way-free frag reads).
// SWAP=true computes C^T (n on (quad,reg), m on l15) for vectorized stores.
// ---------------------------------------------------------------------------
template<bool SWAP>
__device__ __forceinline__ void gemm128_core(
    const u16* __restrict__ Ag, const u16* __restrict__ Bg,   // tile row-0 bases
    f32x4 acc[4][4], u16* As, u16* Bs, int wm, int wn, int l15, int quad)
{
    const int t = threadIdx.x;
    const int w = t >> 6, lane = t & 63;
    const int lr = lane >> 2, lc = lane & 3;
    const int r0 = w * 16 + lr;            // rows 0..63   (issue 0)
    const int r1 = 64 + w * 16 + lr;       // rows 64..127 (issue 1)
    const int g0 = (lc + r0) & 3, g1 = (lc + r1) & 3;
    const u16* a0 = Ag + (size_t)r0 * CH + g0 * 8;
    const u16* a1 = Ag + (size_t)r1 * CH + g1 * 8;
    const u16* b0 = Bg + (size_t)r0 * CH + g0 * 8;
    const u16* b1 = Bg + (size_t)r1 * CH + g1 * 8;
    u16* lA0 = As + w * 512;               // 16 rows * 32 u16 = 1 KB per wave-issue
    u16* lA1 = As + 2048 + w * 512;
    u16* lB0 = Bs + w * 512;
    u16* lB1 = Bs + 2048 + w * 512;

#pragma unroll
    for (int mi = 0; mi < 4; mi++)
#pragma unroll
        for (int ni = 0; ni < 4; ni++) { f32x4 z = {0.f,0.f,0.f,0.f}; acc[mi][ni] = z; }

    for (int k0 = 0; k0 < CH; k0 += 32) {
        __syncthreads();                   // prev iter's frag reads done
        gload16(a0 + k0, lA0);
        gload16(a1 + k0, lA1);
        gload16(b0 + k0, lB0);
        gload16(b1 + k0, lB1);
        __syncthreads();                   // drains vmcnt (loads landed)
        bf16x8 af[4], bfr[4];
#pragma unroll
        for (int mi = 0; mi < 4; mi++) {
            const int ra = wm * 64 + mi * 16 + l15;
            af[mi] = *(const bf16x8*)&As[ra * 32 + ((quad - ra) & 3) * 8];
        }
#pragma unroll
        for (int ni = 0; ni < 4; ni++) {
            const int rb = wn * 64 + ni * 16 + l15;
            bfr[ni] = *(const bf16x8*)&Bs[rb * 32 + ((quad - rb) & 3) * 8];
        }
#pragma unroll
        for (int mi = 0; mi < 4; mi++)
#pragma unroll
            for (int ni = 0; ni < 4; ni++)
                acc[mi][ni] = SWAP
                    ? __builtin_amdgcn_mfma_f32_16x16x32_bf16(bfr[ni], af[mi], acc[mi][ni], 0, 0, 0)
                    : __builtin_amdgcn_mfma_f32_16x16x32_bf16(af[mi], bfr[ni], acc[mi][ni], 0, 0, 0);
    }
}

// ---------------------------------------------------------------------------
// Kernel 1: QKV projection. grid (18,64), block 256.
// Q/K: SWAP path -> vectorized natural stores [BH][SEQ][D] (Q pre-scaled).
// V: standard path -> vectorized transposed stores [BH][D][SEQ].
// ---------------------------------------------------------------------------
__global__ __launch_bounds__(256) void qkv_gemm(
    const u16* __restrict__ x, const u16* __restrict__ w, const u16* __restrict__ bias,
    u16* __restrict__ Qn, u16* __restrict__ Kn, u16* __restrict__ Vt)
{
    __shared__ u16 As[128 * 32];
    __shared__ u16 Bs[128 * 32];
    const int t = threadIdx.x, lane = t & 63, wv = t >> 6;
    const int l15 = lane & 15, quad = lane >> 4;
    const int wm = wv >> 1, wn = wv & 1;
    const int m0 = blockIdx.y * 128, n0 = blockIdx.x * 128;
    const int which = n0 / CH;                 // 0=q 1=k 2=v (block-uniform)
    const int h     = ((n0 % CH) >> 6) + wn;   // wave-uniform
    const int b     = m0 >> 10;
    const size_t bh = (size_t)b * NH + h;
    const int sq0   = m0 & 1023;
    f32x4 acc[4][4];

    if (which == 2) {
        gemm128_core<false>(x + (size_t)m0 * CH, w + (size_t)n0 * CH,
                            acc, As, Bs, wm, wn, l15, quad);
        float bv[4];
#pragma unroll
        for (int ni = 0; ni < 4; ni++) bv[ni] = ld1(bias + n0 + wn * 64 + ni * 16 + l15);
#pragma unroll
        for (int mi = 0; mi < 4; mi++) {
            const int seq = sq0 + wm * 64 + mi * 16 + quad * 4;
#pragma unroll
            for (int ni = 0; ni < 4; ni++) {
                const int d = ni * 16 + l15;
                st4v(&Vt[(bh * HD + d) * SEQ + seq],
                     acc[mi][ni][0] + bv[ni], acc[mi][ni][1] + bv[ni],
                     acc[mi][ni][2] + bv[ni], acc[mi][ni][3] + bv[ni]);
            }
        }
    } else {
        gemm128_core<true>(x + (size_t)m0 * CH, w + (size_t)n0 * CH,
                           acc, As, Bs, wm, wn, l15, quad);
        u16* T2 = which ? Kn : Qn;
        const float qsc = which ? 1.0f : 0.125f;   // D^-0.5 folded into q
        float bvr[4][4];
#pragma unroll
        for (int ni = 0; ni < 4; ni++)
#pragma unroll
            for (int r = 0; r < 4; r++)
                bvr[ni][r] = ld1(bias + n0 + wn * 64 + ni * 16 + quad * 4 + r);
#pragma unroll
        for (int mi = 0; mi < 4; mi++) {
            const int seq = sq0 + wm * 64 + mi * 16 + l15;
#pragma unroll
            for (int ni = 0; ni < 4; ni++) {
                const int dbase = ni * 16 + quad * 4;
                st4v(&T2[(bh * SEQ + seq) * HD + dbase],
                     (acc[mi][ni][0] + bvr[ni][0]) * qsc,
                     (acc[mi][ni][1] + bvr[ni][1]) * qsc,
                     (acc[mi][ni][2] + bvr[ni][2]) * qsc,
                     (acc[mi][ni][3] + bvr[ni][3]) * qsc);
            }
        }
    }
}

// ---------------------------------------------------------------------------
// Kernel 2: MFMA attention. grid (8,96), block 256.
// K/V staged in LDS via pre-barrier register loads (latency hides under the
// PREVIOUS tile's compute — removing this staging regressed 70.8->120 us in
// round 1: direct global frag loads expose L2 latency on the MFMA path).
// QK^T operand-swapped: S^T[j on (quad,r)][i on l15]; P packed with
// v_cvt_pk_bf16_f32 into [i][j] LDS (8x ds_write_b64/tile vs 32x scalar,
// conflicts 3.98M->2.36M measured), rl is a plain per-lane accumulate.
// PV/AV swapped operands -> D[d on (quad,r)][i on l15], vectorized AO stores.
// ---------------------------------------------------------------------------
__global__ __launch_bounds__(256) void attn_kernel(
    const u16* __restrict__ Qn, const u16* __restrict__ Kn, const u16* __restrict__ Vt,
    const u16* __restrict__ Ab, u16* __restrict__ AO)
{
    __shared__ u16 Ks[64 * 72];        // K tile [j][d], stride 72 (bank floor)
    __shared__ u16 Vs[64 * 72];        // V tile [d][j], stride 72
    __shared__ u16 Ps[4 * 32 * 72];    // per-wave P [i][j], stride 72

    const int qb = blockIdx.x;
    const int y  = blockIdx.y;
    const int hh = y >> 3, b = y & 7;           // A-locality decode (same XCD)
    const size_t bh = (size_t)b * NH + hh;
    const int t  = threadIdx.x;
    const int w  = t >> 6, lane = t & 63;
    const int l15 = lane & 15, quad = lane >> 4;
    const int sr = t >> 2, sc = (t & 3) * 16;   // staging row / col
    const int i0g = qb * 128 + w * 32;          // wave's first query (in-batch)
    u16* Psw = Ps + w * 32 * 72;

    const u16* Abr = Ab + (size_t)hh * SEQ * SEQ;

    // Q fragments, loaded once (Qn pre-scaled by D^-0.5). Same registers serve
    // as the B-operand of mfma(K, Q): A-frag of Q == B-frag of Q^T.
    bf16x8 qa[2][2];
#pragma unroll
    for (int isub = 0; isub < 2; isub++)
#pragma unroll
        for (int db = 0; db < 2; db++)
            qa[isub][db] = *(const bf16x8*)(Qn +
                (bh * SEQ + i0g + isub * 16 + l15) * HD + db * 32 + quad * 8);

    f32x4 Op[2][4], Oa[2][4];
#pragma unroll
    for (int i = 0; i < 2; i++)
#pragma unroll
        for (int d = 0; d < 4; d++) { f32x4 z = {0.f,0.f,0.f,0.f}; Op[i][d] = z; Oa[i][d] = z; }
    float rl[2] = {0.f, 0.f};

    for (int kt = 0; kt < 16; kt++) {
        const int j0 = kt * 64;
        // A-bias fragments (B-operand of mfma(v, a)); latency overlaps staging+QK
        bf16x8 afr[2][2];
#pragma unroll
        for (int jb = 0; jb < 2; jb++)
#pragma unroll
            for (int isub = 0; isub < 2; isub++)
                afr[jb][isub] = *(const bf16x8*)(Abr +
                    (size_t)(i0g + isub * 16 + l15) * SEQ + j0 + jb * 32 + quad * 8);

        // K/V staging loads issued BEFORE the barrier: global latency hides
        // under the previous tile's QK/PV compute (async-STAGE split).
        const u16* kp = Kn + (bh * SEQ + j0 + sr) * HD + sc;
        const u16* vp = Vt + (bh * HD + sr) * SEQ + j0 + sc;
        const uint4 k0v = *(const uint4*)kp, k1v = *(const uint4*)(kp + 8);
        const uint4 v0v = *(const uint4*)vp, v1v = *(const uint4*)(vp + 8);
        __syncthreads();                       // prev iter's K/V frag reads done
        *(uint4*)&Ks[sr * 72 + sc] = k0v; *(uint4*)&Ks[sr * 72 + sc + 8] = k1v;
        *(uint4*)&Vs[sr * 72 + sc] = v0v; *(uint4*)&Vs[sr * 72 + sc + 8] = v1v;
        __syncthreads();

        // ---- QK^T swapped: S^T[j = j16*16+quad*4+r][i = isub*16+l15]
#pragma unroll
        for (int j16 = 0; j16 < 4; j16++) {
            const bf16x8 kf0 = *(const bf16x8*)&Ks[(j16 * 16 + l15) * 72 + quad * 8];
            const bf16x8 kf1 = *(const bf16x8*)&Ks[(j16 * 16 + l15) * 72 + 32 + quad * 8];
#pragma unroll
            for (int isub = 0; isub < 2; isub++) {
                f32x4 s = {0.f, 0.f, 0.f, 0.f};
                __builtin_amdgcn_s_setprio(1);
                s = __builtin_amdgcn_mfma_f32_16x16x32_bf16(kf0, qa[isub][0], s, 0, 0, 0);
                s = __builtin_amdgcn_mfma_f32_16x16x32_bf16(kf1, qa[isub][1], s, 0, 0, 0);
                __builtin_amdgcn_s_setprio(0);
                const float p0 = __expf(fminf(s[0], 60.f));  // no inf, ever
                const float p1 = __expf(fminf(s[1], 60.f));
                const float p2 = __expf(fminf(s[2], 60.f));
                const float p3 = __expf(fminf(s[3], 60.f));
                rl[isub] += (p0 + p1) + (p2 + p3);
                uint2 u; u.x = cvtpk(p0, p1); u.y = cvtpk(p2, p3);
                *(uint2*)&Psw[(isub * 16 + l15) * 72 + j16 * 16 + quad * 4] = u;
            }
        }

        // ---- PV + AV, swapped operands: D[d on (quad,r)][i on l15]
#pragma unroll
        for (int jb = 0; jb < 2; jb++) {
            const bf16x8 pf0 = *(const bf16x8*)&Psw[(l15) * 72 + jb * 32 + quad * 8];
            const bf16x8 pf1 = *(const bf16x8*)&Psw[(16 + l15) * 72 + jb * 32 + quad * 8];
            __builtin_amdgcn_s_setprio(1);
#pragma unroll
            for (int d16 = 0; d16 < 4; d16++) {
                const bf16x8 vf = *(const bf16x8*)&Vs[(d16 * 16 + l15) * 72 + jb * 32 + quad * 8];
                Op[0][d16] = __builtin_amdgcn_mfma_f32_16x16x32_bf16(vf, pf0, Op[0][d16], 0, 0, 0);
                Oa[0][d16] = __builtin_amdgcn_mfma_f32_16x16x32_bf16(vf, afr[jb][0], Oa[0][d16], 0, 0, 0);
                Op[1][d16] = __builtin_amdgcn_mfma_f32_16x16x32_bf16(vf, pf1, Op[1][d16], 0, 0, 0);
                Oa[1][d16] = __builtin_amdgcn_mfma_f32_16x16x32_bf16(vf, afr[jb][1], Oa[1][d16], 0, 0, 0);
            }
            __builtin_amdgcn_s_setprio(0);
        }
    }

    // ---- finalize: rl held per-lane for col i = isub*16+l15; sum the 4 quads
    float inv[2];
#pragma unroll
    for (int isub = 0; isub < 2; isub++) {
        float v = rl[isub];
        v += __shfl_xor(v, 16);
        v += __shfl_xor(v, 32);
        inv[isub] = 1.f / v;
    }
#pragma unroll
    for (int isub = 0; isub < 2; isub++) {
        const int n = i0g + isub * 16 + l15;
#pragma unroll
        for (int d16 = 0; d16 < 4; d16++)
            st4v(&AO[((size_t)b * SEQ + n) * CH + hh * HD + d16 * 16 + quad * 4],
                 Op[isub][d16][0] * inv[isub] + Oa[isub][d16][0],
                 Op[isub][d16][1] * inv[isub] + Oa[isub][d16][1],
                 Op[isub][d16][2] * inv[isub] + Oa[isub][d16][2],
                 Op[isub][d16][3] * inv[isub] + Oa[isub][d16][3]);
    }
}

// ---------------------------------------------------------------------------
// Kernel 3: out = AO @ proj_w^T + proj_b. grid (6,64), block 256. SWAP path
// -> vectorized float4/ushort4 stores. Unified: runtime branch on dtype flag
// in the epilogue (one launch instead of two).
// ---------------------------------------------------------------------------
__global__ __launch_bounds__(256) void proj_all(
    const int* __restrict__ flag,
    const u16* __restrict__ AO, const u16* __restrict__ w, const u16* __restrict__ bias,
    void* __restrict__ outv)
{
    __shared__ u16 As[128 * 32];
    __shared__ u16 Bs[128 * 32];
    const int isbf = *flag;
    const int t = threadIdx.x, lane = t & 63, wv = t >> 6;
    const int l15 = lane & 15, quad = lane >> 4;
    const int wm = wv >> 1, wn = wv & 1;
    const int m0 = blockIdx.y * 128, n0 = blockIdx.x * 128;

    f32x4 acc[4][4];
    gemm128_core<true>(AO + (size_t)m0 * CH, w + (size_t)n0 * CH,
                       acc, As, Bs, wm, wn, l15, quad);

    float bvr[4][4];
#pragma unroll
    for (int ni = 0; ni < 4; ni++)
#pragma unroll
        for (int r = 0; r < 4; r++)
            bvr[ni][r] = ld1(bias + n0 + wn * 64 + ni * 16 + quad * 4 + r);
#pragma unroll
    for (int mi = 0; mi < 4; mi++) {
        const int m = m0 + wm * 64 + mi * 16 + l15;
#pragma unroll
        for (int ni = 0; ni < 4; ni++) {
            const int n = n0 + wn * 64 + ni * 16 + quad * 4;
            if (isbf)
                st4v((u16*)outv + (size_t)m * CH + n,
                     acc[mi][ni][0] + bvr[ni][0], acc[mi][ni][1] + bvr[ni][1],
                     acc[mi][ni][2] + bvr[ni][2], acc[mi][ni][3] + bvr[ni][3]);
            else
                st4v((float*)outv + (size_t)m * CH + n,
                     acc[mi][ni][0] + bvr[ni][0], acc[mi][ni][1] + bvr[ni][1],
                     acc[mi][ni][2] + bvr[ni][2], acc[mi][ni][3] + bvr[ni][3]);
        }
    }
}

// ---------------------------------------------------------------------------
extern "C" void kernel_launch(void* const* d_in, const int* in_sizes, int n_in,
                              void* d_out, int out_size, void* d_ws, size_t ws_size,
                              hipStream_t stream) {
    (void)in_sizes; (void)n_in; (void)out_size; (void)ws_size;
    u16* ws = (u16*)d_ws;
    u16* xb   = ws;                 // 6,291,456
    u16* wqb  = ws + 6291456;       // 1,769,472
    u16* bqb  = ws + 8060928;       // 2,304
    u16* Ab   = ws + 8063232;       // 12,582,912
    u16* pwb  = ws + 20646144;      // 589,824
    u16* pbb  = ws + 21235968;      // 768
    u16* arena_end = ws + 21236736;
    const size_t S1 = (size_t)NB * NH * SEQ * HD;   // 6,291,456
    u16* Qn = arena_end;            // [BH][SEQ][D] bf16, pre-scaled
    u16* Kn = Qn + S1;              // [BH][SEQ][D]
    u16* Vt = Kn + S1;              // [BH][D][SEQ]
    u16* AO = Vt + S1;              // [B][SEQ][C]
    int* flag = (int*)(AO + S1);

    detect_kernel<<<dim3(1), dim3(256), 0, stream>>>((const u32*)d_in[0], flag);

    const dim3 blk(256);
    prep_all<<<dim3(4096), blk, 0, stream>>>(flag,
        d_in[0], d_in[1], d_in[2], d_in[3], d_in[4], d_in[5], ws);

    qkv_gemm<<<dim3(QKVN / 128, (NB * SEQ) / 128), blk, 0, stream>>>(
        xb, wqb, bqb, Qn, Kn, Vt);
    attn_kernel<<<dim3(SEQ / 128, BHT), blk, 0, stream>>>(Qn, Kn, Vt, Ab, AO);

    proj_all<<<dim3(CH / 128, (NB * SEQ) / 128), blk, 0, stream>>>(
        flag, AO, pwb, pbb, d_out);
}

// Round 3
// 280.668 us; speedup vs baseline: 1.1617x; 1.0241x over previous
//
#include <hip/hip_runtime.h>
#include <math.h>

#define NB   8
#define SEQ  1024
#define CH   768
#define NH   12
#define HD   64
#define BHT  (NB * NH)    // 96
#define QKVN 2304         // 3*CH

typedef unsigned short u16;
typedef unsigned int   u32;
typedef __attribute__((ext_vector_type(8))) short bf16x8;  // 8 bf16 (4 VGPRs)
typedef __attribute__((ext_vector_type(4))) float f32x4;   // MFMA acc

__device__ __forceinline__ float bf2f(u32 s) {
    union { u32 u; float f; } v; v.u = s << 16; return v.f;
}
__device__ __forceinline__ u16 f2bf(float f) {
    union { float f; u32 u; } v; v.f = f;
    u32 u = v.u;
    return (u16)((u + 0x7fffu + ((u >> 16) & 1u)) >> 16);  // RNE, finite inputs
}
// packed f32x2 -> bf16x2 (RNE), single VALU instr
__device__ __forceinline__ u32 cvtpk(float lo, float hi) {
    u32 r;
    asm("v_cvt_pk_bf16_f32 %0, %1, %2" : "=v"(r) : "v"(lo), "v"(hi));
    return r;
}
__device__ __forceinline__ float ld1(const u16* p) { return bf2f((u32)*p); }
__device__ __forceinline__ void st1(u16* p, float v) { *p = f2bf(v); }
__device__ __forceinline__ void st4v(u16* p, float a, float b, float c, float d) {
    ushort4 o; o.x = f2bf(a); o.y = f2bf(b); o.z = f2bf(c); o.w = f2bf(d);
    *(ushort4*)p = o;
}
__device__ __forceinline__ void st4v(float* p, float a, float b, float c, float d) {
    float4 o; o.x = a; o.y = b; o.z = c; o.w = d;
    *(float4*)p = o;
}
// async global->LDS, 16B per lane, dest = wave-uniform base + lane*16
__device__ __forceinline__ void gload16(const u16* g, u16* l) {
    __builtin_amdgcn_global_load_lds(
        (const __attribute__((address_space(1))) void*)g,
        (__attribute__((address_space(3))) void*)l, 16, 0, 0);
}

// ---------------------------------------------------------------------------
// dtype detect (proven): flag 1 = bf16 inputs, 0 = fp32 inputs
// ---------------------------------------------------------------------------
__global__ void detect_kernel(const u32* __restrict__ x, int* __restrict__ flag) {
    __shared__ int cnt;
    if (threadIdx.x == 0) cnt = 0;
    __syncthreads();
    int c = 0;
    for (int i = threadIdx.x; i < 2048; i += 256) {
        const u32 e0 = (x[i] >> 7) & 0xFFu;
        c += (e0 >= 110u && e0 <= 132u) ? 1 : 0;
    }
    atomicAdd(&cnt, c);
    __syncthreads();
    if (threadIdx.x == 0) *flag = (cnt > 1024) ? 1 : 0;
}

// ---------------------------------------------------------------------------
// Prep: inputs -> one contiguous bf16 arena in ws. Unified (one launch):
// block-uniform branch on dtype flag.
// ---------------------------------------------------------------------------
#define PREP_V4 5309184
__device__ __forceinline__ void prep_seg(size_t v, const size_t e0[6],
                                         int* segp, size_t* offp) {
    int seg = 5;
    if      (v < 1572864) seg = 0;
    else if (v < 2015232) seg = 1;
    else if (v < 2015808) seg = 2;
    else if (v < 5161536) seg = 3;
    else if (v < 5308992) seg = 4;
    *segp = seg; *offp = v * 4 - e0[seg];
}

__global__ __launch_bounds__(256) void prep_all(
    const int* __restrict__ flag,
    const void* __restrict__ s0, const void* __restrict__ s1, const void* __restrict__ s2,
    const void* __restrict__ s3, const void* __restrict__ s4, const void* __restrict__ s5,
    u16* __restrict__ dst)
{
    const size_t e0[6] = {0, 6291456, 8060928, 8063232, 20646144, 21235968};
    if (*flag != 0) {
        const u16* const srcs[6] = {(const u16*)s0, (const u16*)s1, (const u16*)s2,
                                    (const u16*)s3, (const u16*)s4, (const u16*)s5};
        for (size_t v = blockIdx.x * 256 + threadIdx.x; v < PREP_V4; v += (size_t)gridDim.x * 256) {
            int seg; size_t off;
            prep_seg(v, e0, &seg, &off);
            *(ushort4*)(dst + v * 4) = *(const ushort4*)(srcs[seg] + off);
        }
    } else {
        const float* const srcs[6] = {(const float*)s0, (const float*)s1, (const float*)s2,
                                      (const float*)s3, (const float*)s4, (const float*)s5};
        for (size_t v = blockIdx.x * 256 + threadIdx.x; v < PREP_V4; v += (size_t)gridDim.x * 256) {
            int seg; size_t off;
            prep_seg(v, e0, &seg, &off);
            const float4 f = *(const float4*)(srcs[seg] + off);
            ushort4 o; o.x = f2bf(f.x); o.y = f2bf(f.y); o.z = f2bf(f.z); o.w = f2bf(f.w);
            *(ushort4*)(dst + v * 4) = o;
        }
    }
}

// ---------------------------------------------------------------------------
// 128x128 MFMA GEMM core, m97-style global_load_lds staging.
// LDS [128 rows][32 u16], unpadded; 16B k-chunk at column c of row r holds
// global chunk (c + r) & 3  (source-side rotation -> 2-way-free frag reads).
// SWAP=true computes C^T (n on (quad,reg), m on l15) for vectorized stores.
// ---------------------------------------------------------------------------
template<bool SWAP>
__device__ __forceinline__ void gemm128_core(
    const u16* __restrict__ Ag, const u16* __restrict__ Bg,   // tile row-0 bases
    f32x4 acc[4][4], u16* As, u16* Bs, int wm, int wn, int l15, int quad)
{
    const int t = threadIdx.x;
    const int w = t >> 6, lane = t & 63;
    const int lr = lane >> 2, lc = lane & 3;
    const int r0 = w * 16 + lr;            // rows 0..63   (issue 0)
    const int r1 = 64 + w * 16 + lr;       // rows 64..127 (issue 1)
    const int g0 = (lc + r0) & 3, g1 = (lc + r1) & 3;
    const u16* a0 = Ag + (size_t)r0 * CH + g0 * 8;
    const u16* a1 = Ag + (size_t)r1 * CH + g1 * 8;
    const u16* b0 = Bg + (size_t)r0 * CH + g0 * 8;
    const u16* b1 = Bg + (size_t)r1 * CH + g1 * 8;
    u16* lA0 = As + w * 512;               // 16 rows * 32 u16 = 1 KB per wave-issue
    u16* lA1 = As + 2048 + w * 512;
    u16* lB0 = Bs + w * 512;
    u16* lB1 = Bs + 2048 + w * 512;

#pragma unroll
    for (int mi = 0; mi < 4; mi++)
#pragma unroll
        for (int ni = 0; ni < 4; ni++) { f32x4 z = {0.f,0.f,0.f,0.f}; acc[mi][ni] = z; }

    for (int k0 = 0; k0 < CH; k0 += 32) {
        __syncthreads();                   // prev iter's frag reads done
        gload16(a0 + k0, lA0);
        gload16(a1 + k0, lA1);
        gload16(b0 + k0, lB0);
        gload16(b1 + k0, lB1);
        __syncthreads();                   // drains vmcnt (loads landed)
        bf16x8 af[4], bfr[4];
#pragma unroll
        for (int mi = 0; mi < 4; mi++) {
            const int ra = wm * 64 + mi * 16 + l15;
            af[mi] = *(const bf16x8*)&As[ra * 32 + ((quad - ra) & 3) * 8];
        }
#pragma unroll
        for (int ni = 0; ni < 4; ni++) {
            const int rb = wn * 64 + ni * 16 + l15;
            bfr[ni] = *(const bf16x8*)&Bs[rb * 32 + ((quad - rb) & 3) * 8];
        }
#pragma unroll
        for (int mi = 0; mi < 4; mi++)
#pragma unroll
            for (int ni = 0; ni < 4; ni++)
                acc[mi][ni] = SWAP
                    ? __builtin_amdgcn_mfma_f32_16x16x32_bf16(bfr[ni], af[mi], acc[mi][ni], 0, 0, 0)
                    : __builtin_amdgcn_mfma_f32_16x16x32_bf16(af[mi], bfr[ni], acc[mi][ni], 0, 0, 0);
    }
}

// ---------------------------------------------------------------------------
// Kernel 1: QKV projection. grid (18,64), block 256.
// Q/K: SWAP path -> vectorized natural stores [BH][SEQ][D].
// Q pre-scaled by D^-0.5 * log2(e): attn computes exp2 directly.
// V: standard path -> vectorized transposed stores [BH][D][SEQ].
// ---------------------------------------------------------------------------
__global__ __launch_bounds__(256) void qkv_gemm(
    const u16* __restrict__ x, const u16* __restrict__ w, const u16* __restrict__ bias,
    u16* __restrict__ Qn, u16* __restrict__ Kn, u16* __restrict__ Vt)
{
    __shared__ u16 As[128 * 32];
    __shared__ u16 Bs[128 * 32];
    const int t = threadIdx.x, lane = t & 63, wv = t >> 6;
    const int l15 = lane & 15, quad = lane >> 4;
    const int wm = wv >> 1, wn = wv & 1;
    const int m0 = blockIdx.y * 128, n0 = blockIdx.x * 128;
    const int which = n0 / CH;                 // 0=q 1=k 2=v (block-uniform)
    const int h     = ((n0 % CH) >> 6) + wn;   // wave-uniform
    const int b     = m0 >> 10;
    const size_t bh = (size_t)b * NH + h;
    const int sq0   = m0 & 1023;
    f32x4 acc[4][4];

    if (which == 2) {
        gemm128_core<false>(x + (size_t)m0 * CH, w + (size_t)n0 * CH,
                            acc, As, Bs, wm, wn, l15, quad);
        float bv[4];
#pragma unroll
        for (int ni = 0; ni < 4; ni++) bv[ni] = ld1(bias + n0 + wn * 64 + ni * 16 + l15);
#pragma unroll
        for (int mi = 0; mi < 4; mi++) {
            const int seq = sq0 + wm * 64 + mi * 16 + quad * 4;
#pragma unroll
            for (int ni = 0; ni < 4; ni++) {
                const int d = ni * 16 + l15;
                st4v(&Vt[(bh * HD + d) * SEQ + seq],
                     acc[mi][ni][0] + bv[ni], acc[mi][ni][1] + bv[ni],
                     acc[mi][ni][2] + bv[ni], acc[mi][ni][3] + bv[ni]);
            }
        }
    } else {
        gemm128_core<true>(x + (size_t)m0 * CH, w + (size_t)n0 * CH,
                           acc, As, Bs, wm, wn, l15, quad);
        u16* T2 = which ? Kn : Qn;
        // D^-0.5 * log2(e) folded into q => attn uses native v_exp_f32 (exp2)
        const float qsc = which ? 1.0f : 0.18033688011112042f;
        float bvr[4][4];
#pragma unroll
        for (int ni = 0; ni < 4; ni++)
#pragma unroll
            for (int r = 0; r < 4; r++)
                bvr[ni][r] = ld1(bias + n0 + wn * 64 + ni * 16 + quad * 4 + r);
#pragma unroll
        for (int mi = 0; mi < 4; mi++) {
            const int seq = sq0 + wm * 64 + mi * 16 + l15;
#pragma unroll
            for (int ni = 0; ni < 4; ni++) {
                const int dbase = ni * 16 + quad * 4;
                st4v(&T2[(bh * SEQ + seq) * HD + dbase],
                     (acc[mi][ni][0] + bvr[ni][0]) * qsc,
                     (acc[mi][ni][1] + bvr[ni][1]) * qsc,
                     (acc[mi][ni][2] + bvr[ni][2]) * qsc,
                     (acc[mi][ni][3] + bvr[ni][3]) * qsc);
            }
        }
    }
}

// ---------------------------------------------------------------------------
// Kernel 2: MFMA attention (round-0 structure, verbatim except two 1-instr
// substitutions in the softmax chain). grid (8,96), block 256.
// K/V staged in LDS via pre-barrier register loads (async-STAGE: global
// latency hides under the previous tile's compute — removing this regressed
// 70.8->120 us; swapped-QK/packed-P graft regressed 70.8->81.4 us).
// Softmax: s is already in log2 domain (Q pre-scale) -> exp2f = bare
// v_exp_f32; P->bf16 via v_cvt_pk_bf16_f32(p,p) = 1 VALU vs 3-op bit-hack.
// ---------------------------------------------------------------------------
__global__ __launch_bounds__(256) void attn_kernel(
    const u16* __restrict__ Qn, const u16* __restrict__ Kn, const u16* __restrict__ Vt,
    const u16* __restrict__ Ab, u16* __restrict__ AO)
{
    __shared__ u16 Ks[64 * 72];        // K tile [j][d], stride 72
    __shared__ u16 Vs[64 * 72];        // V tile [d][j], stride 72
    __shared__ u16 Ps[4 * 32 * 72];    // per-wave P [i][j], stride 72

    const int qb = blockIdx.x;
    const int y  = blockIdx.y;
    const int hh = y >> 3, b = y & 7;           // A-locality decode
    const size_t bh = (size_t)b * NH + hh;
    const int t  = threadIdx.x;
    const int w  = t >> 6, lane = t & 63;
    const int l15 = lane & 15, quad = lane >> 4;
    const int sr = t >> 2, sc = (t & 3) * 16;   // staging row / col
    const int i0g = qb * 128 + w * 32;          // wave's first query (in-batch)
    u16* Psw = Ps + w * 32 * 72;

    // Q a-frags, loaded once (Qn pre-scaled by D^-0.5 * log2e)
    bf16x8 qa[2][2];
#pragma unroll
    for (int isub = 0; isub < 2; isub++)
#pragma unroll
        for (int db = 0; db < 2; db++)
            qa[isub][db] = *(const bf16x8*)(Qn +
                (bh * SEQ + i0g + isub * 16 + l15) * HD + db * 32 + quad * 8);

    f32x4 Op[2][4], Oa[2][4];
#pragma unroll
    for (int i = 0; i < 2; i++)
#pragma unroll
        for (int d = 0; d < 4; d++) { f32x4 z = {0.f,0.f,0.f,0.f}; Op[i][d] = z; Oa[i][d] = z; }
    float rl[2][4] = {{0.f,0.f,0.f,0.f},{0.f,0.f,0.f,0.f}};

    for (int kt = 0; kt < 16; kt++) {
        const int j0 = kt * 64;
        // A-operand prefetch (bf16 straight loads; latency overlaps staging+QK)
        bf16x8 afr[2][2];
#pragma unroll
        for (int jb = 0; jb < 2; jb++)
#pragma unroll
            for (int isub = 0; isub < 2; isub++)
                afr[jb][isub] = *(const bf16x8*)(Ab +
                    ((size_t)hh * SEQ + i0g + isub * 16 + l15) * SEQ
                    + j0 + jb * 32 + quad * 8);

        const u16* kp = Kn + (bh * SEQ + j0 + sr) * HD + sc;
        const u16* vp = Vt + (bh * HD + sr) * SEQ + j0 + sc;
        const uint4 k0v = *(const uint4*)kp, k1v = *(const uint4*)(kp + 8);
        const uint4 v0v = *(const uint4*)vp, v1v = *(const uint4*)(vp + 8);
        __syncthreads();                       // prev iter's K/V frag reads done
        *(uint4*)&Ks[sr * 72 + sc] = k0v; *(uint4*)&Ks[sr * 72 + sc + 8] = k1v;
        *(uint4*)&Vs[sr * 72 + sc] = v0v; *(uint4*)&Vs[sr * 72 + sc + 8] = v1v;
        __syncthreads();

        // ---- QK^T (standard order: i on (quad,r), j on l15); exp2; P -> LDS
#pragma unroll
        for (int j16 = 0; j16 < 4; j16++) {
            const bf16x8 kf0 = *(const bf16x8*)&Ks[(j16 * 16 + l15) * 72 + quad * 8];
            const bf16x8 kf1 = *(const bf16x8*)&Ks[(j16 * 16 + l15) * 72 + 32 + quad * 8];
#pragma unroll
            for (int isub = 0; isub < 2; isub++) {
                f32x4 s = {0.f, 0.f, 0.f, 0.f};
                s = __builtin_amdgcn_mfma_f32_16x16x32_bf16(qa[isub][0], kf0, s, 0, 0, 0);
                s = __builtin_amdgcn_mfma_f32_16x16x32_bf16(qa[isub][1], kf1, s, 0, 0, 0);
#pragma unroll
                for (int r = 0; r < 4; r++) {
                    const float p = exp2f(fminf(s[r], 86.6f));  // no inf, ever
                    rl[isub][r] += p;
                    Psw[(isub * 16 + quad * 4 + r) * 72 + j16 * 16 + l15] = (u16)cvtpk(p, p);
                }
            }
        }

        // ---- PV + AV, swapped operands: D[d on (quad,r)][i on l15]
#pragma unroll
        for (int jb = 0; jb < 2; jb++) {
            bf16x8 pf[2];
#pragma unroll
            for (int isub = 0; isub < 2; isub++)
                pf[isub] = *(const bf16x8*)&Psw[(isub * 16 + l15) * 72 + jb * 32 + quad * 8];
#pragma unroll
            for (int d16 = 0; d16 < 4; d16++) {
                const bf16x8 vf = *(const bf16x8*)&Vs[(d16 * 16 + l15) * 72 + jb * 32 + quad * 8];
#pragma unroll
                for (int isub = 0; isub < 2; isub++) {
                    Op[isub][d16] = __builtin_amdgcn_mfma_f32_16x16x32_bf16(vf, pf[isub], Op[isub][d16], 0, 0, 0);
                    Oa[isub][d16] = __builtin_amdgcn_mfma_f32_16x16x32_bf16(vf, afr[jb][isub], Oa[isub][d16], 0, 0, 0);
                }
            }
        }
    }

    // ---- finalize: reduce rl over l15, redistribute to i=l15, vector store
    float inv[2];
#pragma unroll
    for (int isub = 0; isub < 2; isub++) {
        float rr[4];
#pragma unroll
        for (int r = 0; r < 4; r++) {
            float v = rl[isub][r];
            v += __shfl_xor(v, 1); v += __shfl_xor(v, 2);
            v += __shfl_xor(v, 4); v += __shfl_xor(v, 8);
            rr[r] = v;                          // full sum for i = isub*16+quad*4+r
        }
        const int src = (l15 >> 2) << 4;        // lane 0 of the quad holding my i
        const float t0 = __shfl(rr[0], src), t1 = __shfl(rr[1], src);
        const float t2 = __shfl(rr[2], src), t3 = __shfl(rr[3], src);
        const float sel = (l15 & 2) ? ((l15 & 1) ? t3 : t2)
                                    : ((l15 & 1) ? t1 : t0);
        inv[isub] = 1.f / sel;
    }
#pragma unroll
    for (int isub = 0; isub < 2; isub++) {
        const int n = i0g + isub * 16 + l15;
#pragma unroll
        for (int d16 = 0; d16 < 4; d16++)
            st4v(&AO[((size_t)b * SEQ + n) * CH + hh * HD + d16 * 16 + quad * 4],
                 Op[isub][d16][0] * inv[isub] + Oa[isub][d16][0],
                 Op[isub][d16][1] * inv[isub] + Oa[isub][d16][1],
                 Op[isub][d16][2] * inv[isub] + Oa[isub][d16][2],
                 Op[isub][d16][3] * inv[isub] + Oa[isub][d16][3]);
    }
}

// ---------------------------------------------------------------------------
// Kernel 3: out = AO @ proj_w^T + proj_b. grid (6,64), block 256. SWAP path
// -> vectorized float4/ushort4 stores. Unified: runtime branch on dtype flag
// in the epilogue (one launch instead of two).
// ---------------------------------------------------------------------------
__global__ __launch_bounds__(256) void proj_all(
    const int* __restrict__ flag,
    const u16* __restrict__ AO, const u16* __restrict__ w, const u16* __restrict__ bias,
    void* __restrict__ outv)
{
    __shared__ u16 As[128 * 32];
    __shared__ u16 Bs[128 * 32];
    const int isbf = *flag;
    const int t = threadIdx.x, lane = t & 63, wv = t >> 6;
    const int l15 = lane & 15, quad = lane >> 4;
    const int wm = wv >> 1, wn = wv & 1;
    const int m0 = blockIdx.y * 128, n0 = blockIdx.x * 128;

    f32x4 acc[4][4];
    gemm128_core<true>(AO + (size_t)m0 * CH, w + (size_t)n0 * CH,
                       acc, As, Bs, wm, wn, l15, quad);

    float bvr[4][4];
#pragma unroll
    for (int ni = 0; ni < 4; ni++)
#pragma unroll
        for (int r = 0; r < 4; r++)
            bvr[ni][r] = ld1(bias + n0 + wn * 64 + ni * 16 + quad * 4 + r);
#pragma unroll
    for (int mi = 0; mi < 4; mi++) {
        const int m = m0 + wm * 64 + mi * 16 + l15;
#pragma unroll
        for (int ni = 0; ni < 4; ni++) {
            const int n = n0 + wn * 64 + ni * 16 + quad * 4;
            if (isbf)
                st4v((u16*)outv + (size_t)m * CH + n,
                     acc[mi][ni][0] + bvr[ni][0], acc[mi][ni][1] + bvr[ni][1],
                     acc[mi][ni][2] + bvr[ni][2], acc[mi][ni][3] + bvr[ni][3]);
            else
                st4v((float*)outv + (size_t)m * CH + n,
                     acc[mi][ni][0] + bvr[ni][0], acc[mi][ni][1] + bvr[ni][1],
                     acc[mi][ni][2] + bvr[ni][2], acc[mi][ni][3] + bvr[ni][3]);
        }
    }
}

// ---------------------------------------------------------------------------
extern "C" void kernel_launch(void* const* d_in, const int* in_sizes, int n_in,
                              void* d_out, int out_size, void* d_ws, size_t ws_size,
                              hipStream_t stream) {
    (void)in_sizes; (void)n_in; (void)out_size; (void)ws_size;
    u16* ws = (u16*)d_ws;
    u16* xb   = ws;                 // 6,291,456
    u16* wqb  = ws + 6291456;       // 1,769,472
    u16* bqb  = ws + 8060928;       // 2,304
    u16* Ab   = ws + 8063232;       // 12,582,912
    u16* pwb  = ws + 20646144;      // 589,824
    u16* pbb  = ws + 21235968;      // 768
    u16* arena_end = ws + 21236736;
    const size_t S1 = (size_t)NB * NH * SEQ * HD;   // 6,291,456
    u16* Qn = arena_end;            // [BH][SEQ][D] bf16, pre-scaled
    u16* Kn = Qn + S1;              // [BH][SEQ][D]
    u16* Vt = Kn + S1;              // [BH][D][SEQ]
    u16* AO = Vt + S1;              // [B][SEQ][C]
    int* flag = (int*)(AO + S1);

    detect_kernel<<<dim3(1), dim3(256), 0, stream>>>((const u32*)d_in[0], flag);

    const dim3 blk(256);
    prep_all<<<dim3(4096), blk, 0, stream>>>(flag,
        d_in[0], d_in[1], d_in[2], d_in[3], d_in[4], d_in[5], ws);

    qkv_gemm<<<dim3(QKVN / 128, (NB * SEQ) / 128), blk, 0, stream>>>(
        xb, wqb, bqb, Qn, Kn, Vt);
    attn_kernel<<<dim3(SEQ / 128, BHT), blk, 0, stream>>>(Qn, Kn, Vt, Ab, AO);

    proj_all<<<dim3(CH / 128, (NB * SEQ) / 128), blk, 0, stream>>>(
        flag, AO, pwb, pbb, d_out);
}

// Round 4
// 279.875 us; speedup vs baseline: 1.1650x; 1.0028x over previous
//
#include <hip/hip_runtime.h>
#include <math.h>

#define NB   8
#define SEQ  1024
#define CH   768
#define NH   12
#define HD   64
#define BHT  (NB * NH)    // 96
#define QKVN 2304         // 3*CH

typedef unsigned short u16;
typedef unsigned int   u32;
typedef __attribute__((ext_vector_type(8))) short bf16x8;  // 8 bf16 (4 VGPRs)
typedef __attribute__((ext_vector_type(4))) float f32x4;   // MFMA acc

__device__ __forceinline__ float bf2f(u32 s) {
    union { u32 u; float f; } v; v.u = s << 16; return v.f;
}
__device__ __forceinline__ u16 f2bf(float f) {
    union { float f; u32 u; } v; v.f = f;
    u32 u = v.u;
    return (u16)((u + 0x7fffu + ((u >> 16) & 1u)) >> 16);  // RNE, finite inputs
}
__device__ __forceinline__ float ld1(const u16* p) { return bf2f((u32)*p); }
__device__ __forceinline__ void st4v(u16* p, float a, float b, float c, float d) {
    ushort4 o; o.x = f2bf(a); o.y = f2bf(b); o.z = f2bf(c); o.w = f2bf(d);
    *(ushort4*)p = o;
}
__device__ __forceinline__ void st4v(float* p, float a, float b, float c, float d) {
    float4 o; o.x = a; o.y = b; o.z = c; o.w = d;
    *(float4*)p = o;
}
// async global->LDS, 16B per lane, dest = wave-uniform base + lane*16
__device__ __forceinline__ void gload16(const u16* g, u16* l) {
    __builtin_amdgcn_global_load_lds(
        (const __attribute__((address_space(1))) void*)g,
        (__attribute__((address_space(3))) void*)l, 16, 0, 0);
}

// ---------------------------------------------------------------------------
// dtype detect (proven): flag 1 = bf16 inputs, 0 = fp32 inputs
// ---------------------------------------------------------------------------
__global__ void detect_kernel(const u32* __restrict__ x, int* __restrict__ flag) {
    __shared__ int cnt;
    if (threadIdx.x == 0) cnt = 0;
    __syncthreads();
    int c = 0;
    for (int i = threadIdx.x; i < 2048; i += 256) {
        const u32 e0 = (x[i] >> 7) & 0xFFu;
        c += (e0 >= 110u && e0 <= 132u) ? 1 : 0;
    }
    atomicAdd(&cnt, c);
    __syncthreads();
    if (threadIdx.x == 0) *flag = (cnt > 1024) ? 1 : 0;
}

// ---------------------------------------------------------------------------
// Prep: inputs -> one contiguous bf16 arena in ws. Unified (one launch):
// block-uniform branch on dtype flag.
// ---------------------------------------------------------------------------
#define PREP_V4 5309184
__device__ __forceinline__ void prep_seg(size_t v, const size_t e0[6],
                                         int* segp, size_t* offp) {
    int seg = 5;
    if      (v < 1572864) seg = 0;
    else if (v < 2015232) seg = 1;
    else if (v < 2015808) seg = 2;
    else if (v < 5161536) seg = 3;
    else if (v < 5308992) seg = 4;
    *segp = seg; *offp = v * 4 - e0[seg];
}

__global__ __launch_bounds__(256) void prep_all(
    const int* __restrict__ flag,
    const void* __restrict__ s0, const void* __restrict__ s1, const void* __restrict__ s2,
    const void* __restrict__ s3, const void* __restrict__ s4, const void* __restrict__ s5,
    u16* __restrict__ dst)
{
    const size_t e0[6] = {0, 6291456, 8060928, 8063232, 20646144, 21235968};
    if (*flag != 0) {
        const u16* const srcs[6] = {(const u16*)s0, (const u16*)s1, (const u16*)s2,
                                    (const u16*)s3, (const u16*)s4, (const u16*)s5};
        for (size_t v = blockIdx.x * 256 + threadIdx.x; v < PREP_V4; v += (size_t)gridDim.x * 256) {
            int seg; size_t off;
            prep_seg(v, e0, &seg, &off);
            *(ushort4*)(dst + v * 4) = *(const ushort4*)(srcs[seg] + off);
        }
    } else {
        const float* const srcs[6] = {(const float*)s0, (const float*)s1, (const float*)s2,
                                      (const float*)s3, (const float*)s4, (const float*)s5};
        for (size_t v = blockIdx.x * 256 + threadIdx.x; v < PREP_V4; v += (size_t)gridDim.x * 256) {
            int seg; size_t off;
            prep_seg(v, e0, &seg, &off);
            const float4 f = *(const float4*)(srcs[seg] + off);
            ushort4 o; o.x = f2bf(f.x); o.y = f2bf(f.y); o.z = f2bf(f.z); o.w = f2bf(f.w);
            *(ushort4*)(dst + v * 4) = o;
        }
    }
}

// ---------------------------------------------------------------------------
// 128x128 MFMA GEMM core, m97-style global_load_lds staging.
// LDS [128 rows][32 u16], unpadded; 16B k-chunk at column c of row r holds
// global chunk (c + r) & 3  (source-side rotation -> 2-way-free frag reads).
// SWAP=true computes C^T (n on (quad,reg), m on l15) for vectorized stores.
// ---------------------------------------------------------------------------
template<bool SWAP>
__device__ __forceinline__ void gemm128_core(
    const u16* __restrict__ Ag, const u16* __restrict__ Bg,   // tile row-0 bases
    f32x4 acc[4][4], u16* As, u16* Bs, int wm, int wn, int l15, int quad)
{
    const int t = threadIdx.x;
    const int w = t >> 6, lane = t & 63;
    const int lr = lane >> 2, lc = lane & 3;
    const int r0 = w * 16 + lr;            // rows 0..63   (issue 0)
    const int r1 = 64 + w * 16 + lr;       // rows 64..127 (issue 1)
    const int g0 = (lc + r0) & 3, g1 = (lc + r1) & 3;
    const u16* a0 = Ag + (size_t)r0 * CH + g0 * 8;
    const u16* a1 = Ag + (size_t)r1 * CH + g1 * 8;
    const u16* b0 = Bg + (size_t)r0 * CH + g0 * 8;
    const u16* b1 = Bg + (size_t)r1 * CH + g1 * 8;
    u16* lA0 = As + w * 512;               // 16 rows * 32 u16 = 1 KB per wave-issue
    u16* lA1 = As + 2048 + w * 512;
    u16* lB0 = Bs + w * 512;
    u16* lB1 = Bs + 2048 + w * 512;

#pragma unroll
    for (int mi = 0; mi < 4; mi++)
#pragma unroll
        for (int ni = 0; ni < 4; ni++) { f32x4 z = {0.f,0.f,0.f,0.f}; acc[mi][ni] = z; }

    for (int k0 = 0; k0 < CH; k0 += 32) {
        __syncthreads();                   // prev iter's frag reads done
        gload16(a0 + k0, lA0);
        gload16(a1 + k0, lA1);
        gload16(b0 + k0, lB0);
        gload16(b1 + k0, lB1);
        __syncthreads();                   // drains vmcnt (loads landed)
        bf16x8 af[4], bfr[4];
#pragma unroll
        for (int mi = 0; mi < 4; mi++) {
            const int ra = wm * 64 + mi * 16 + l15;
            af[mi] = *(const bf16x8*)&As[ra * 32 + ((quad - ra) & 3) * 8];
        }
#pragma unroll
        for (int ni = 0; ni < 4; ni++) {
            const int rb = wn * 64 + ni * 16 + l15;
            bfr[ni] = *(const bf16x8*)&Bs[rb * 32 + ((quad - rb) & 3) * 8];
        }
#pragma unroll
        for (int mi = 0; mi < 4; mi++)
#pragma unroll
            for (int ni = 0; ni < 4; ni++)
                acc[mi][ni] = SWAP
                    ? __builtin_amdgcn_mfma_f32_16x16x32_bf16(bfr[ni], af[mi], acc[mi][ni], 0, 0, 0)
                    : __builtin_amdgcn_mfma_f32_16x16x32_bf16(af[mi], bfr[ni], acc[mi][ni], 0, 0, 0);
    }
}

// ---------------------------------------------------------------------------
// Kernel 1: QKV projection. grid (18,64), block 256.
// Q/K: SWAP path -> vectorized natural stores [BH][SEQ][D] (Q pre-scaled).
// V: standard path -> vectorized transposed stores [BH][D][SEQ].
// ---------------------------------------------------------------------------
__global__ __launch_bounds__(256) void qkv_gemm(
    const u16* __restrict__ x, const u16* __restrict__ w, const u16* __restrict__ bias,
    u16* __restrict__ Qn, u16* __restrict__ Kn, u16* __restrict__ Vt)
{
    __shared__ u16 As[128 * 32];
    __shared__ u16 Bs[128 * 32];
    const int t = threadIdx.x, lane = t & 63, wv = t >> 6;
    const int l15 = lane & 15, quad = lane >> 4;
    const int wm = wv >> 1, wn = wv & 1;
    const int m0 = blockIdx.y * 128, n0 = blockIdx.x * 128;
    const int which = n0 / CH;                 // 0=q 1=k 2=v (block-uniform)
    const int h     = ((n0 % CH) >> 6) + wn;   // wave-uniform
    const int b     = m0 >> 10;
    const size_t bh = (size_t)b * NH + h;
    const int sq0   = m0 & 1023;
    f32x4 acc[4][4];

    if (which == 2) {
        gemm128_core<false>(x + (size_t)m0 * CH, w + (size_t)n0 * CH,
                            acc, As, Bs, wm, wn, l15, quad);
        float bv[4];
#pragma unroll
        for (int ni = 0; ni < 4; ni++) bv[ni] = ld1(bias + n0 + wn * 64 + ni * 16 + l15);
#pragma unroll
        for (int mi = 0; mi < 4; mi++) {
            const int seq = sq0 + wm * 64 + mi * 16 + quad * 4;
#pragma unroll
            for (int ni = 0; ni < 4; ni++) {
                const int d = ni * 16 + l15;
                st4v(&Vt[(bh * HD + d) * SEQ + seq],
                     acc[mi][ni][0] + bv[ni], acc[mi][ni][1] + bv[ni],
                     acc[mi][ni][2] + bv[ni], acc[mi][ni][3] + bv[ni]);
            }
        }
    } else {
        gemm128_core<true>(x + (size_t)m0 * CH, w + (size_t)n0 * CH,
                           acc, As, Bs, wm, wn, l15, quad);
        u16* T2 = which ? Kn : Qn;
        const float qsc = which ? 1.0f : 0.125f;   // D^-0.5 folded into q
        float bvr[4][4];
#pragma unroll
        for (int ni = 0; ni < 4; ni++)
#pragma unroll
            for (int r = 0; r < 4; r++)
                bvr[ni][r] = ld1(bias + n0 + wn * 64 + ni * 16 + quad * 4 + r);
#pragma unroll
        for (int mi = 0; mi < 4; mi++) {
            const int seq = sq0 + wm * 64 + mi * 16 + l15;
#pragma unroll
            for (int ni = 0; ni < 4; ni++) {
                const int dbase = ni * 16 + quad * 4;
                st4v(&T2[(bh * SEQ + seq) * HD + dbase],
                     (acc[mi][ni][0] + bvr[ni][0]) * qsc,
                     (acc[mi][ni][1] + bvr[ni][1]) * qsc,
                     (acc[mi][ni][2] + bvr[ni][2]) * qsc,
                     (acc[mi][ni][3] + bvr[ni][3]) * qsc);
            }
        }
    }
}

// ---------------------------------------------------------------------------
// Kernel 2: MFMA attention. grid (16,96), block 256 — round-0 inner loop
// VERBATIM (staging, barriers, __expf+f2bf softmax, P round-trip, finalize),
// with per-wave queries halved 32->16 and the grid doubled. Rationale:
// round-0 was grid-bound (768 blocks = 12 waves/CU ceiling, occ 26%, all
// pipes <50%). 1536 blocks + LDS 36.9->27.6 KB lifts resident waves to
// 16-20/CU so barrier/vmcnt drains overlap across blocks. Per-query work
// unchanged; K/V L2 re-reads double (256 KB/bh, L2-resident — free).
// Prior failed variants: no-staging (120us, latency-bound), swapped-QK+
// packed-P (81us, codegen), exp2f+cvtpk (75.5us, fixup VALU).
// ---------------------------------------------------------------------------
__global__ __launch_bounds__(256) void attn_kernel(
    const u16* __restrict__ Qn, const u16* __restrict__ Kn, const u16* __restrict__ Vt,
    const u16* __restrict__ Ab, u16* __restrict__ AO)
{
    __shared__ u16 Ks[64 * 72];        // K tile [j][d], stride 72
    __shared__ u16 Vs[64 * 72];        // V tile [d][j], stride 72
    __shared__ u16 Ps[4 * 16 * 72];    // per-wave P [i][j], stride 72 (16 rows)

    const int qb = blockIdx.x;
    const int y  = blockIdx.y;
    const int hh = y >> 3, b = y & 7;           // A-locality decode
    const size_t bh = (size_t)b * NH + hh;
    const int t  = threadIdx.x;
    const int w  = t >> 6, lane = t & 63;
    const int l15 = lane & 15, quad = lane >> 4;
    const int sr = t >> 2, sc = (t & 3) * 16;   // staging row / col
    const int i0g = qb * 64 + w * 16;           // wave's first query (in-batch)
    u16* Psw = Ps + w * 16 * 72;

    // Q a-frags, loaded once (Qn pre-scaled by D^-0.5); 16 rows per wave
    bf16x8 qa[2];
#pragma unroll
    for (int db = 0; db < 2; db++)
        qa[db] = *(const bf16x8*)(Qn +
            (bh * SEQ + i0g + l15) * HD + db * 32 + quad * 8);

    f32x4 Op[4], Oa[4];
#pragma unroll
    for (int d = 0; d < 4; d++) { f32x4 z = {0.f,0.f,0.f,0.f}; Op[d] = z; Oa[d] = z; }
    float rl[4] = {0.f,0.f,0.f,0.f};

    for (int kt = 0; kt < 16; kt++) {
        const int j0 = kt * 64;
        // A-operand prefetch (bf16 straight loads; latency overlaps staging+QK)
        bf16x8 afr[2];
#pragma unroll
        for (int jb = 0; jb < 2; jb++)
            afr[jb] = *(const bf16x8*)(Ab +
                ((size_t)hh * SEQ + i0g + l15) * SEQ + j0 + jb * 32 + quad * 8);

        // K/V staging loads issued BEFORE the barrier: global latency hides
        // under the previous tile's QK/PV compute (async-STAGE split).
        const u16* kp = Kn + (bh * SEQ + j0 + sr) * HD + sc;
        const u16* vp = Vt + (bh * HD + sr) * SEQ + j0 + sc;
        const uint4 k0v = *(const uint4*)kp, k1v = *(const uint4*)(kp + 8);
        const uint4 v0v = *(const uint4*)vp, v1v = *(const uint4*)(vp + 8);
        __syncthreads();                       // prev iter's K/V frag reads done
        *(uint4*)&Ks[sr * 72 + sc] = k0v; *(uint4*)&Ks[sr * 72 + sc + 8] = k1v;
        *(uint4*)&Vs[sr * 72 + sc] = v0v; *(uint4*)&Vs[sr * 72 + sc + 8] = v1v;
        __syncthreads();

        // ---- QK^T (standard order: i on (quad,r), j on l15); exp; P -> LDS
#pragma unroll
        for (int j16 = 0; j16 < 4; j16++) {
            const bf16x8 kf0 = *(const bf16x8*)&Ks[(j16 * 16 + l15) * 72 + quad * 8];
            const bf16x8 kf1 = *(const bf16x8*)&Ks[(j16 * 16 + l15) * 72 + 32 + quad * 8];
            f32x4 s = {0.f, 0.f, 0.f, 0.f};
            s = __builtin_amdgcn_mfma_f32_16x16x32_bf16(qa[0], kf0, s, 0, 0, 0);
            s = __builtin_amdgcn_mfma_f32_16x16x32_bf16(qa[1], kf1, s, 0, 0, 0);
#pragma unroll
            for (int r = 0; r < 4; r++) {
                const float p = __expf(fminf(s[r], 60.f));  // no inf, ever
                rl[r] += p;
                Psw[(quad * 4 + r) * 72 + j16 * 16 + l15] = f2bf(p);
            }
        }

        // ---- PV + AV, swapped operands: D[d on (quad,r)][i on l15]
#pragma unroll
        for (int jb = 0; jb < 2; jb++) {
            const bf16x8 pf = *(const bf16x8*)&Psw[l15 * 72 + jb * 32 + quad * 8];
#pragma unroll
            for (int d16 = 0; d16 < 4; d16++) {
                const bf16x8 vf = *(const bf16x8*)&Vs[(d16 * 16 + l15) * 72 + jb * 32 + quad * 8];
                Op[d16] = __builtin_amdgcn_mfma_f32_16x16x32_bf16(vf, pf, Op[d16], 0, 0, 0);
                Oa[d16] = __builtin_amdgcn_mfma_f32_16x16x32_bf16(vf, afr[jb], Oa[d16], 0, 0, 0);
            }
        }
    }

    // ---- finalize: reduce rl over l15, redistribute to i=l15, vector store
    float rr[4];
#pragma unroll
    for (int r = 0; r < 4; r++) {
        float v = rl[r];
        v += __shfl_xor(v, 1); v += __shfl_xor(v, 2);
        v += __shfl_xor(v, 4); v += __shfl_xor(v, 8);
        rr[r] = v;                              // full sum for i = quad*4+r
    }
    const int src = (l15 >> 2) << 4;            // lane 0 of the quad holding my i
    const float t0 = __shfl(rr[0], src), t1 = __shfl(rr[1], src);
    const float t2 = __shfl(rr[2], src), t3 = __shfl(rr[3], src);
    const float sel = (l15 & 2) ? ((l15 & 1) ? t3 : t2)
                                : ((l15 & 1) ? t1 : t0);
    const float inv = 1.f / sel;
    const int n = i0g + l15;
#pragma unroll
    for (int d16 = 0; d16 < 4; d16++)
        st4v(&AO[((size_t)b * SEQ + n) * CH + hh * HD + d16 * 16 + quad * 4],
             Op[d16][0] * inv + Oa[d16][0],
             Op[d16][1] * inv + Oa[d16][1],
             Op[d16][2] * inv + Oa[d16][2],
             Op[d16][3] * inv + Oa[d16][3]);
}

// ---------------------------------------------------------------------------
// Kernel 3: out = AO @ proj_w^T + proj_b. grid (6,64), block 256. SWAP path
// -> vectorized float4/ushort4 stores. Unified: runtime branch on dtype flag
// in the epilogue (one launch instead of two).
// ---------------------------------------------------------------------------
__global__ __launch_bounds__(256) void proj_all(
    const int* __restrict__ flag,
    const u16* __restrict__ AO, const u16* __restrict__ w, const u16* __restrict__ bias,
    void* __restrict__ outv)
{
    __shared__ u16 As[128 * 32];
    __shared__ u16 Bs[128 * 32];
    const int isbf = *flag;
    const int t = threadIdx.x, lane = t & 63, wv = t >> 6;
    const int l15 = lane & 15, quad = lane >> 4;
    const int wm = wv >> 1, wn = wv & 1;
    const int m0 = blockIdx.y * 128, n0 = blockIdx.x * 128;

    f32x4 acc[4][4];
    gemm128_core<true>(AO + (size_t)m0 * CH, w + (size_t)n0 * CH,
                       acc, As, Bs, wm, wn, l15, quad);

    float bvr[4][4];
#pragma unroll
    for (int ni = 0; ni < 4; ni++)
#pragma unroll
        for (int r = 0; r < 4; r++)
            bvr[ni][r] = ld1(bias + n0 + wn * 64 + ni * 16 + quad * 4 + r);
#pragma unroll
    for (int mi = 0; mi < 4; mi++) {
        const int m = m0 + wm * 64 + mi * 16 + l15;
#pragma unroll
        for (int ni = 0; ni < 4; ni++) {
            const int n = n0 + wn * 64 + ni * 16 + quad * 4;
            if (isbf)
                st4v((u16*)outv + (size_t)m * CH + n,
                     acc[mi][ni][0] + bvr[ni][0], acc[mi][ni][1] + bvr[ni][1],
                     acc[mi][ni][2] + bvr[ni][2], acc[mi][ni][3] + bvr[ni][3]);
            else
                st4v((float*)outv + (size_t)m * CH + n,
                     acc[mi][ni][0] + bvr[ni][0], acc[mi][ni][1] + bvr[ni][1],
                     acc[mi][ni][2] + bvr[ni][2], acc[mi][ni][3] + bvr[ni][3]);
        }
    }
}

// ---------------------------------------------------------------------------
extern "C" void kernel_launch(void* const* d_in, const int* in_sizes, int n_in,
                              void* d_out, int out_size, void* d_ws, size_t ws_size,
                              hipStream_t stream) {
    (void)in_sizes; (void)n_in; (void)out_size; (void)ws_size;
    u16* ws = (u16*)d_ws;
    u16* xb   = ws;                 // 6,291,456
    u16* wqb  = ws + 6291456;       // 1,769,472
    u16* bqb  = ws + 8060928;       // 2,304
    u16* Ab   = ws + 8063232;       // 12,582,912
    u16* pwb  = ws + 20646144;      // 589,824
    u16* pbb  = ws + 21235968;      // 768
    u16* arena_end = ws + 21236736;
    const size_t S1 = (size_t)NB * NH * SEQ * HD;   // 6,291,456
    u16* Qn = arena_end;            // [BH][SEQ][D] bf16, pre-scaled
    u16* Kn = Qn + S1;              // [BH][SEQ][D]
    u16* Vt = Kn + S1;              // [BH][D][SEQ]
    u16* AO = Vt + S1;              // [B][SEQ][C]
    int* flag = (int*)(AO + S1);

    detect_kernel<<<dim3(1), dim3(256), 0, stream>>>((const u32*)d_in[0], flag);

    const dim3 blk(256);
    prep_all<<<dim3(4096), blk, 0, stream>>>(flag,
        d_in[0], d_in[1], d_in[2], d_in[3], d_in[4], d_in[5], ws);

    qkv_gemm<<<dim3(QKVN / 128, (NB * SEQ) / 128), blk, 0, stream>>>(
        xb, wqb, bqb, Qn, Kn, Vt);
    attn_kernel<<<dim3(SEQ / 64, BHT), blk, 0, stream>>>(Qn, Kn, Vt, Ab, AO);

    proj_all<<<dim3(CH / 128, (NB * SEQ) / 128), blk, 0, stream>>>(
        flag, AO, pwb, pbb, d_out);
}

// Round 5
// 266.103 us; speedup vs baseline: 1.2253x; 1.0518x over previous
//
#include <hip/hip_runtime.h>
#include <math.h>

#define NB   8
#define SEQ  1024
#define CH   768
#define NH   12
#define HD   64
#define BHT  (NB * NH)    // 96
#define QKVN 2304         // 3*CH

typedef unsigned short u16;
typedef unsigned int   u32;
typedef __attribute__((ext_vector_type(8))) short bf16x8;  // 8 bf16 (4 VGPRs)
typedef __attribute__((ext_vector_type(4))) float f32x4;   // MFMA acc

__device__ __forceinline__ float bf2f(u32 s) {
    union { u32 u; float f; } v; v.u = s << 16; return v.f;
}
__device__ __forceinline__ u16 f2bf(float f) {
    union { float f; u32 u; } v; v.f = f;
    u32 u = v.u;
    return (u16)((u + 0x7fffu + ((u >> 16) & 1u)) >> 16);  // RNE, finite inputs
}
__device__ __forceinline__ float ld1(const u16* p) { return bf2f((u32)*p); }
__device__ __forceinline__ void st4v(u16* p, float a, float b, float c, float d) {
    ushort4 o; o.x = f2bf(a); o.y = f2bf(b); o.z = f2bf(c); o.w = f2bf(d);
    *(ushort4*)p = o;
}
__device__ __forceinline__ void st4v(float* p, float a, float b, float c, float d) {
    float4 o; o.x = a; o.y = b; o.z = c; o.w = d;
    *(float4*)p = o;
}
// async global->LDS, 16B per lane, dest = wave-uniform base + lane*16
__device__ __forceinline__ void gload16(const u16* g, u16* l) {
    __builtin_amdgcn_global_load_lds(
        (const __attribute__((address_space(1))) void*)g,
        (__attribute__((address_space(3))) void*)l, 16, 0, 0);
}

// ---------------------------------------------------------------------------
// dtype detect (proven): flag 1 = bf16 inputs, 0 = fp32 inputs
// ---------------------------------------------------------------------------
__global__ void detect_kernel(const u32* __restrict__ x, int* __restrict__ flag) {
    __shared__ int cnt;
    if (threadIdx.x == 0) cnt = 0;
    __syncthreads();
    int c = 0;
    for (int i = threadIdx.x; i < 2048; i += 256) {
        const u32 e0 = (x[i] >> 7) & 0xFFu;
        c += (e0 >= 110u && e0 <= 132u) ? 1 : 0;
    }
    atomicAdd(&cnt, c);
    __syncthreads();
    if (threadIdx.x == 0) *flag = (cnt > 1024) ? 1 : 0;
}

// ---------------------------------------------------------------------------
// Prep: inputs -> one contiguous bf16 arena in ws. Unified (one launch):
// block-uniform branch on dtype flag.
// ---------------------------------------------------------------------------
#define PREP_V4 5309184
__device__ __forceinline__ void prep_seg(size_t v, const size_t e0[6],
                                         int* segp, size_t* offp) {
    int seg = 5;
    if      (v < 1572864) seg = 0;
    else if (v < 2015232) seg = 1;
    else if (v < 2015808) seg = 2;
    else if (v < 5161536) seg = 3;
    else if (v < 5308992) seg = 4;
    *segp = seg; *offp = v * 4 - e0[seg];
}

__global__ __launch_bounds__(256) void prep_all(
    const int* __restrict__ flag,
    const void* __restrict__ s0, const void* __restrict__ s1, const void* __restrict__ s2,
    const void* __restrict__ s3, const void* __restrict__ s4, const void* __restrict__ s5,
    u16* __restrict__ dst)
{
    const size_t e0[6] = {0, 6291456, 8060928, 8063232, 20646144, 21235968};
    if (*flag != 0) {
        const u16* const srcs[6] = {(const u16*)s0, (const u16*)s1, (const u16*)s2,
                                    (const u16*)s3, (const u16*)s4, (const u16*)s5};
        for (size_t v = blockIdx.x * 256 + threadIdx.x; v < PREP_V4; v += (size_t)gridDim.x * 256) {
            int seg; size_t off;
            prep_seg(v, e0, &seg, &off);
            *(ushort4*)(dst + v * 4) = *(const ushort4*)(srcs[seg] + off);
        }
    } else {
        const float* const srcs[6] = {(const float*)s0, (const float*)s1, (const float*)s2,
                                      (const float*)s3, (const float*)s4, (const float*)s5};
        for (size_t v = blockIdx.x * 256 + threadIdx.x; v < PREP_V4; v += (size_t)gridDim.x * 256) {
            int seg; size_t off;
            prep_seg(v, e0, &seg, &off);
            const float4 f = *(const float4*)(srcs[seg] + off);
            ushort4 o; o.x = f2bf(f.x); o.y = f2bf(f.y); o.z = f2bf(f.z); o.w = f2bf(f.w);
            *(ushort4*)(dst + v * 4) = o;
        }
    }
}

// ---------------------------------------------------------------------------
// 128x128 MFMA GEMM core, m97-style global_load_lds staging.
// LDS [128 rows][32 u16], unpadded; 16B k-chunk at column c of row r holds
// global chunk (c + r) & 3  (source-side rotation -> 2-way-free frag reads).
// SWAP=true computes C^T (n on (quad,reg), m on l15) for vectorized stores.
// ---------------------------------------------------------------------------
template<bool SWAP>
__device__ __forceinline__ void gemm128_core(
    const u16* __restrict__ Ag, const u16* __restrict__ Bg,   // tile row-0 bases
    f32x4 acc[4][4], u16* As, u16* Bs, int wm, int wn, int l15, int quad)
{
    const int t = threadIdx.x;
    const int w = t >> 6, lane = t & 63;
    const int lr = lane >> 2, lc = lane & 3;
    const int r0 = w * 16 + lr;            // rows 0..63   (issue 0)
    const int r1 = 64 + w * 16 + lr;       // rows 64..127 (issue 1)
    const int g0 = (lc + r0) & 3, g1 = (lc + r1) & 3;
    const u16* a0 = Ag + (size_t)r0 * CH + g0 * 8;
    const u16* a1 = Ag + (size_t)r1 * CH + g1 * 8;
    const u16* b0 = Bg + (size_t)r0 * CH + g0 * 8;
    const u16* b1 = Bg + (size_t)r1 * CH + g1 * 8;
    u16* lA0 = As + w * 512;               // 16 rows * 32 u16 = 1 KB per wave-issue
    u16* lA1 = As + 2048 + w * 512;
    u16* lB0 = Bs + w * 512;
    u16* lB1 = Bs + 2048 + w * 512;

#pragma unroll
    for (int mi = 0; mi < 4; mi++)
#pragma unroll
        for (int ni = 0; ni < 4; ni++) { f32x4 z = {0.f,0.f,0.f,0.f}; acc[mi][ni] = z; }

    for (int k0 = 0; k0 < CH; k0 += 32) {
        __syncthreads();                   // prev iter's frag reads done
        gload16(a0 + k0, lA0);
        gload16(a1 + k0, lA1);
        gload16(b0 + k0, lB0);
        gload16(b1 + k0, lB1);
        __syncthreads();                   // drains vmcnt (loads landed)
        bf16x8 af[4], bfr[4];
#pragma unroll
        for (int mi = 0; mi < 4; mi++) {
            const int ra = wm * 64 + mi * 16 + l15;
            af[mi] = *(const bf16x8*)&As[ra * 32 + ((quad - ra) & 3) * 8];
        }
#pragma unroll
        for (int ni = 0; ni < 4; ni++) {
            const int rb = wn * 64 + ni * 16 + l15;
            bfr[ni] = *(const bf16x8*)&Bs[rb * 32 + ((quad - rb) & 3) * 8];
        }
#pragma unroll
        for (int mi = 0; mi < 4; mi++)
#pragma unroll
            for (int ni = 0; ni < 4; ni++)
                acc[mi][ni] = SWAP
                    ? __builtin_amdgcn_mfma_f32_16x16x32_bf16(bfr[ni], af[mi], acc[mi][ni], 0, 0, 0)
                    : __builtin_amdgcn_mfma_f32_16x16x32_bf16(af[mi], bfr[ni], acc[mi][ni], 0, 0, 0);
    }
}

// ---------------------------------------------------------------------------
// 128x64 MFMA GEMM core (same staging scheme; B tile is 64 rows -> one
// staging issue per wave). Used by proj, whose N=768 gives only 6 n-blocks
// at 128 width (384 blocks = 1.5/CU, imbalanced). 64-wide -> 768 blocks.
// ---------------------------------------------------------------------------
template<bool SWAP>
__device__ __forceinline__ void gemm128x64_core(
    const u16* __restrict__ Ag, const u16* __restrict__ Bg,
    f32x4 acc[4][2], u16* As, u16* Bs, int wm, int wn, int l15, int quad)
{
    const int t = threadIdx.x;
    const int w = t >> 6, lane = t & 63;
    const int lr = lane >> 2, lc = lane & 3;
    const int r0 = w * 16 + lr;            // rows 0..63
    const int r1 = 64 + w * 16 + lr;       // rows 64..127 (A only)
    const int g0 = (lc + r0) & 3, g1 = (lc + r1) & 3;
    const u16* a0 = Ag + (size_t)r0 * CH + g0 * 8;
    const u16* a1 = Ag + (size_t)r1 * CH + g1 * 8;
    const u16* b0 = Bg + (size_t)r0 * CH + g0 * 8;   // B rows 0..63
    u16* lA0 = As + w * 512;
    u16* lA1 = As + 2048 + w * 512;
    u16* lB0 = Bs + w * 512;

#pragma unroll
    for (int mi = 0; mi < 4; mi++)
#pragma unroll
        for (int ni = 0; ni < 2; ni++) { f32x4 z = {0.f,0.f,0.f,0.f}; acc[mi][ni] = z; }

    for (int k0 = 0; k0 < CH; k0 += 32) {
        __syncthreads();
        gload16(a0 + k0, lA0);
        gload16(a1 + k0, lA1);
        gload16(b0 + k0, lB0);
        __syncthreads();
        bf16x8 af[4], bfr[2];
#pragma unroll
        for (int mi = 0; mi < 4; mi++) {
            const int ra = wm * 64 + mi * 16 + l15;
            af[mi] = *(const bf16x8*)&As[ra * 32 + ((quad - ra) & 3) * 8];
        }
#pragma unroll
        for (int ni = 0; ni < 2; ni++) {
            const int rb = wn * 32 + ni * 16 + l15;
            bfr[ni] = *(const bf16x8*)&Bs[rb * 32 + ((quad - rb) & 3) * 8];
        }
#pragma unroll
        for (int mi = 0; mi < 4; mi++)
#pragma unroll
            for (int ni = 0; ni < 2; ni++)
                acc[mi][ni] = SWAP
                    ? __builtin_amdgcn_mfma_f32_16x16x32_bf16(bfr[ni], af[mi], acc[mi][ni], 0, 0, 0)
                    : __builtin_amdgcn_mfma_f32_16x16x32_bf16(af[mi], bfr[ni], acc[mi][ni], 0, 0, 0);
    }
}

// ---------------------------------------------------------------------------
// Kernel 1: QKV projection. grid (18,64), block 256, XCD-swizzled:
// each XCD owns 8 contiguous m-rows x all 18 n-tiles, so a row's A-panel
// (192 KB) is fetched into ONE XCD's L2 instead of ~8 (1152%8==0, bijective).
// Q/K: SWAP path -> vectorized natural stores [BH][SEQ][D] (Q pre-scaled).
// V: standard path -> vectorized transposed stores [BH][D][SEQ].
// ---------------------------------------------------------------------------
__global__ __launch_bounds__(256) void qkv_gemm(
    const u16* __restrict__ x, const u16* __restrict__ w, const u16* __restrict__ bias,
    u16* __restrict__ Qn, u16* __restrict__ Kn, u16* __restrict__ Vt)
{
    __shared__ u16 As[128 * 32];
    __shared__ u16 Bs[128 * 32];
    const int id  = blockIdx.y * 18 + blockIdx.x;   // 0..1151
    const int xcd = id & 7, seq0 = id >> 3;         // seq0 0..143
    const int by  = xcd * 8 + seq0 / 18;            // 0..63
    const int bx  = seq0 % 18;                      // 0..17
    const int t = threadIdx.x, lane = t & 63, wv = t >> 6;
    const int l15 = lane & 15, quad = lane >> 4;
    const int wm = wv >> 1, wn = wv & 1;
    const int m0 = by * 128, n0 = bx * 128;
    const int which = n0 / CH;                 // 0=q 1=k 2=v (block-uniform)
    const int h     = ((n0 % CH) >> 6) + wn;   // wave-uniform
    const int b     = m0 >> 10;
    const size_t bh = (size_t)b * NH + h;
    const int sq0   = m0 & 1023;
    f32x4 acc[4][4];

    if (which == 2) {
        gemm128_core<false>(x + (size_t)m0 * CH, w + (size_t)n0 * CH,
                            acc, As, Bs, wm, wn, l15, quad);
        float bv[4];
#pragma unroll
        for (int ni = 0; ni < 4; ni++) bv[ni] = ld1(bias + n0 + wn * 64 + ni * 16 + l15);
#pragma unroll
        for (int mi = 0; mi < 4; mi++) {
            const int seq = sq0 + wm * 64 + mi * 16 + quad * 4;
#pragma unroll
            for (int ni = 0; ni < 4; ni++) {
                const int d = ni * 16 + l15;
                st4v(&Vt[(bh * HD + d) * SEQ + seq],
                     acc[mi][ni][0] + bv[ni], acc[mi][ni][1] + bv[ni],
                     acc[mi][ni][2] + bv[ni], acc[mi][ni][3] + bv[ni]);
            }
        }
    } else {
        gemm128_core<true>(x + (size_t)m0 * CH, w + (size_t)n0 * CH,
                           acc, As, Bs, wm, wn, l15, quad);
        u16* T2 = which ? Kn : Qn;
        const float qsc = which ? 1.0f : 0.125f;   // D^-0.5 folded into q
        float bvr[4][4];
#pragma unroll
        for (int ni = 0; ni < 4; ni++)
#pragma unroll
            for (int r = 0; r < 4; r++)
                bvr[ni][r] = ld1(bias + n0 + wn * 64 + ni * 16 + quad * 4 + r);
#pragma unroll
        for (int mi = 0; mi < 4; mi++) {
            const int seq = sq0 + wm * 64 + mi * 16 + l15;
#pragma unroll
            for (int ni = 0; ni < 4; ni++) {
                const int dbase = ni * 16 + quad * 4;
                st4v(&T2[(bh * SEQ + seq) * HD + dbase],
                     (acc[mi][ni][0] + bvr[ni][0]) * qsc,
                     (acc[mi][ni][1] + bvr[ni][1]) * qsc,
                     (acc[mi][ni][2] + bvr[ni][2]) * qsc,
                     (acc[mi][ni][3] + bvr[ni][3]) * qsc);
            }
        }
    }
}

// ---------------------------------------------------------------------------
// Kernel 2: MFMA attention — round-0 structure VERBATIM (proven 70.8 us;
// every perturbation measured worse: no-staging 120, swapped-QK+packed-P
// 81.4, exp2f+cvtpk 75.5, half-tile/2x-grid 76.7). grid (8,96), block 256.
// x=qb=id%8 already gives per-XCD Ab-slab locality. PV/AV use swapped
// operands -> vectorized AO stores.
// ---------------------------------------------------------------------------
__global__ __launch_bounds__(256) void attn_kernel(
    const u16* __restrict__ Qn, const u16* __restrict__ Kn, const u16* __restrict__ Vt,
    const u16* __restrict__ Ab, u16* __restrict__ AO)
{
    __shared__ u16 Ks[64 * 72];        // K tile [j][d], stride 72
    __shared__ u16 Vs[64 * 72];        // V tile [d][j], stride 72
    __shared__ u16 Ps[4 * 32 * 72];    // per-wave P [i][j], stride 72

    const int qb = blockIdx.x;
    const int y  = blockIdx.y;
    const int hh = y >> 3, b = y & 7;           // A-locality decode
    const size_t bh = (size_t)b * NH + hh;
    const int t  = threadIdx.x;
    const int w  = t >> 6, lane = t & 63;
    const int l15 = lane & 15, quad = lane >> 4;
    const int sr = t >> 2, sc = (t & 3) * 16;   // staging row / col
    const int i0g = qb * 128 + w * 32;          // wave's first query (in-batch)
    u16* Psw = Ps + w * 32 * 72;

    // Q a-frags, loaded once (Qn pre-scaled by D^-0.5)
    bf16x8 qa[2][2];
#pragma unroll
    for (int isub = 0; isub < 2; isub++)
#pragma unroll
        for (int db = 0; db < 2; db++)
            qa[isub][db] = *(const bf16x8*)(Qn +
                (bh * SEQ + i0g + isub * 16 + l15) * HD + db * 32 + quad * 8);

    f32x4 Op[2][4], Oa[2][4];
#pragma unroll
    for (int i = 0; i < 2; i++)
#pragma unroll
        for (int d = 0; d < 4; d++) { f32x4 z = {0.f,0.f,0.f,0.f}; Op[i][d] = z; Oa[i][d] = z; }
    float rl[2][4] = {{0.f,0.f,0.f,0.f},{0.f,0.f,0.f,0.f}};

    for (int kt = 0; kt < 16; kt++) {
        const int j0 = kt * 64;
        // A-operand prefetch (bf16 straight loads; latency overlaps staging+QK)
        bf16x8 afr[2][2];
#pragma unroll
        for (int jb = 0; jb < 2; jb++)
#pragma unroll
            for (int isub = 0; isub < 2; isub++)
                afr[jb][isub] = *(const bf16x8*)(Ab +
                    ((size_t)hh * SEQ + i0g + isub * 16 + l15) * SEQ
                    + j0 + jb * 32 + quad * 8);

        const u16* kp = Kn + (bh * SEQ + j0 + sr) * HD + sc;
        const u16* vp = Vt + (bh * HD + sr) * SEQ + j0 + sc;
        const uint4 k0v = *(const uint4*)kp, k1v = *(const uint4*)(kp + 8);
        const uint4 v0v = *(const uint4*)vp, v1v = *(const uint4*)(vp + 8);
        __syncthreads();                       // prev iter's K/V frag reads done
        *(uint4*)&Ks[sr * 72 + sc] = k0v; *(uint4*)&Ks[sr * 72 + sc + 8] = k1v;
        *(uint4*)&Vs[sr * 72 + sc] = v0v; *(uint4*)&Vs[sr * 72 + sc + 8] = v1v;
        __syncthreads();

        // ---- QK^T (standard order: i on (quad,r), j on l15); exp; P -> LDS
#pragma unroll
        for (int j16 = 0; j16 < 4; j16++) {
            const bf16x8 kf0 = *(const bf16x8*)&Ks[(j16 * 16 + l15) * 72 + quad * 8];
            const bf16x8 kf1 = *(const bf16x8*)&Ks[(j16 * 16 + l15) * 72 + 32 + quad * 8];
#pragma unroll
            for (int isub = 0; isub < 2; isub++) {
                f32x4 s = {0.f, 0.f, 0.f, 0.f};
                s = __builtin_amdgcn_mfma_f32_16x16x32_bf16(qa[isub][0], kf0, s, 0, 0, 0);
                s = __builtin_amdgcn_mfma_f32_16x16x32_bf16(qa[isub][1], kf1, s, 0, 0, 0);
#pragma unroll
                for (int r = 0; r < 4; r++) {
                    const float p = __expf(fminf(s[r], 60.f));  // no inf, ever
                    rl[isub][r] += p;
                    Psw[(isub * 16 + quad * 4 + r) * 72 + j16 * 16 + l15] = f2bf(p);
                }
            }
        }

        // ---- PV + AV, swapped operands: D[d on (quad,r)][i on l15]
#pragma unroll
        for (int jb = 0; jb < 2; jb++) {
            bf16x8 pf[2];
#pragma unroll
            for (int isub = 0; isub < 2; isub++)
                pf[isub] = *(const bf16x8*)&Psw[(isub * 16 + l15) * 72 + jb * 32 + quad * 8];
#pragma unroll
            for (int d16 = 0; d16 < 4; d16++) {
                const bf16x8 vf = *(const bf16x8*)&Vs[(d16 * 16 + l15) * 72 + jb * 32 + quad * 8];
#pragma unroll
                for (int isub = 0; isub < 2; isub++) {
                    Op[isub][d16] = __builtin_amdgcn_mfma_f32_16x16x32_bf16(vf, pf[isub], Op[isub][d16], 0, 0, 0);
                    Oa[isub][d16] = __builtin_amdgcn_mfma_f32_16x16x32_bf16(vf, afr[jb][isub], Oa[isub][d16], 0, 0, 0);
                }
            }
        }
    }

    // ---- finalize: reduce rl over l15, redistribute to i=l15, vector store
    float inv[2];
#pragma unroll
    for (int isub = 0; isub < 2; isub++) {
        float rr[4];
#pragma unroll
        for (int r = 0; r < 4; r++) {
            float v = rl[isub][r];
            v += __shfl_xor(v, 1); v += __shfl_xor(v, 2);
            v += __shfl_xor(v, 4); v += __shfl_xor(v, 8);
            rr[r] = v;                          // full sum for i = isub*16+quad*4+r
        }
        const int src = (l15 >> 2) << 4;        // lane 0 of the quad holding my i
        const float t0 = __shfl(rr[0], src), t1 = __shfl(rr[1], src);
        const float t2 = __shfl(rr[2], src), t3 = __shfl(rr[3], src);
        const float sel = (l15 & 2) ? ((l15 & 1) ? t3 : t2)
                                    : ((l15 & 1) ? t1 : t0);
        inv[isub] = 1.f / sel;
    }
#pragma unroll
    for (int isub = 0; isub < 2; isub++) {
        const int n = i0g + isub * 16 + l15;
#pragma unroll
        for (int d16 = 0; d16 < 4; d16++)
            st4v(&AO[((size_t)b * SEQ + n) * CH + hh * HD + d16 * 16 + quad * 4],
                 Op[isub][d16][0] * inv[isub] + Oa[isub][d16][0],
                 Op[isub][d16][1] * inv[isub] + Oa[isub][d16][1],
                 Op[isub][d16][2] * inv[isub] + Oa[isub][d16][2],
                 Op[isub][d16][3] * inv[isub] + Oa[isub][d16][3]);
    }
}

// ---------------------------------------------------------------------------
// Kernel 3: out = AO @ proj_w^T + proj_b. grid (12,64), block 256.
// Retiled 128x128 -> 128x64: 384 blocks (1.5/CU, imbalanced) -> 768 blocks
// (exactly 3/CU). XCD-swizzled like qkv (768%8==0, bijective). SWAP path ->
// vectorized float4/ushort4 stores; runtime dtype-flag branch in epilogue.
// ---------------------------------------------------------------------------
__global__ __launch_bounds__(256) void proj_all(
    const int* __restrict__ flag,
    const u16* __restrict__ AO, const u16* __restrict__ w, const u16* __restrict__ bias,
    void* __restrict__ outv)
{
    __shared__ u16 As[128 * 32];
    __shared__ u16 Bs[64 * 32];
    const int isbf = *flag;
    const int id  = blockIdx.y * 12 + blockIdx.x;   // 0..767
    const int xcd = id & 7, seq0 = id >> 3;         // seq0 0..95
    const int by  = xcd * 8 + seq0 / 12;            // 0..63
    const int bx  = seq0 % 12;                      // 0..11
    const int t = threadIdx.x, lane = t & 63, wv = t >> 6;
    const int l15 = lane & 15, quad = lane >> 4;
    const int wm = wv >> 1, wn = wv & 1;
    const int m0 = by * 128, n0 = bx * 64;

    f32x4 acc[4][2];
    gemm128x64_core<true>(AO + (size_t)m0 * CH, w + (size_t)n0 * CH,
                          acc, As, Bs, wm, wn, l15, quad);

    float bvr[2][4];
#pragma unroll
    for (int ni = 0; ni < 2; ni++)
#pragma unroll
        for (int r = 0; r < 4; r++)
            bvr[ni][r] = ld1(bias + n0 + wn * 32 + ni * 16 + quad * 4 + r);
#pragma unroll
    for (int mi = 0; mi < 4; mi++) {
        const int m = m0 + wm * 64 + mi * 16 + l15;
#pragma unroll
        for (int ni = 0; ni < 2; ni++) {
            const int n = n0 + wn * 32 + ni * 16 + quad * 4;
            if (isbf)
                st4v((u16*)outv + (size_t)m * CH + n,
                     acc[mi][ni][0] + bvr[ni][0], acc[mi][ni][1] + bvr[ni][1],
                     acc[mi][ni][2] + bvr[ni][2], acc[mi][ni][3] + bvr[ni][3]);
            else
                st4v((float*)outv + (size_t)m * CH + n,
                     acc[mi][ni][0] + bvr[ni][0], acc[mi][ni][1] + bvr[ni][1],
                     acc[mi][ni][2] + bvr[ni][2], acc[mi][ni][3] + bvr[ni][3]);
        }
    }
}

// ---------------------------------------------------------------------------
extern "C" void kernel_launch(void* const* d_in, const int* in_sizes, int n_in,
                              void* d_out, int out_size, void* d_ws, size_t ws_size,
                              hipStream_t stream) {
    (void)in_sizes; (void)n_in; (void)out_size; (void)ws_size;
    u16* ws = (u16*)d_ws;
    u16* xb   = ws;                 // 6,291,456
    u16* wqb  = ws + 6291456;       // 1,769,472
    u16* bqb  = ws + 8060928;       // 2,304
    u16* Ab   = ws + 8063232;       // 12,582,912
    u16* pwb  = ws + 20646144;      // 589,824
    u16* pbb  = ws + 21235968;      // 768
    u16* arena_end = ws + 21236736;
    const size_t S1 = (size_t)NB * NH * SEQ * HD;   // 6,291,456
    u16* Qn = arena_end;            // [BH][SEQ][D] bf16, pre-scaled
    u16* Kn = Qn + S1;              // [BH][SEQ][D]
    u16* Vt = Kn + S1;              // [BH][D][SEQ]
    u16* AO = Vt + S1;              // [B][SEQ][C]
    int* flag = (int*)(AO + S1);

    detect_kernel<<<dim3(1), dim3(256), 0, stream>>>((const u32*)d_in[0], flag);

    const dim3 blk(256);
    prep_all<<<dim3(4096), blk, 0, stream>>>(flag,
        d_in[0], d_in[1], d_in[2], d_in[3], d_in[4], d_in[5], ws);

    qkv_gemm<<<dim3(QKVN / 128, (NB * SEQ) / 128), blk, 0, stream>>>(
        xb, wqb, bqb, Qn, Kn, Vt);
    attn_kernel<<<dim3(SEQ / 128, BHT), blk, 0, stream>>>(Qn, Kn, Vt, Ab, AO);

    proj_all<<<dim3(CH / 64, (NB * SEQ) / 128), blk, 0, stream>>>(
        flag, AO, pwb, pbb, d_out);
}